// Round 18
// baseline (495.134 us; speedup 1.0000x reference)
//
#include <hip/hip_runtime.h>
#include <hip/hip_bf16.h>

typedef unsigned short u16;
typedef __attribute__((ext_vector_type(8))) short bf16x8;
typedef __attribute__((ext_vector_type(4))) float f32x4;

#define NH 12
#define SCALE 0.1767766952966369f

// ---- ws layout (bytes) ----
#define UNIT 20992
#define WS_R0    ((size_t)0)
#define WS_QKVB  ((size_t)12288 * UNIT)                 // 257,949,696
#define WS_PROJB (WS_QKVB + (size_t)3 * 12 * 49152)     // +1,769,472
#define WS_NEED  (WS_PROJB + (size_t)12 * 49152)        // = 260,308,992

// split fp32 -> bf16 hi/lo via native RNE casts
__device__ __forceinline__ void split2(float x, u16& h, u16& l) {
    __hip_bfloat16 hb = __float2bfloat16(x);
    float hf = __bfloat162float(hb);
    __hip_bfloat16 lb = __float2bfloat16(x - hf);
    h = __bfloat16_as_ushort(hb);
    l = __bfloat16_as_ushort(lb);
}
__device__ __forceinline__ void split8(const float* v, bf16x8& hi, bf16x8& lo) {
    #pragma unroll
    for (int j = 0; j < 8; ++j) {
        u16 h, l; split2(v[j], h, l);
        hi[j] = (short)h; lo[j] = (short)l;
    }
}

// async global->LDS, 16B per lane
__device__ __forceinline__ void gload16(const char* g, char* l) {
    __builtin_amdgcn_global_load_lds(
        (const __attribute__((address_space(1))) unsigned*)g,
        (__attribute__((address_space(3))) unsigned*)l, 16, 0, 0);
}

// fallback-path swizzle
__device__ __forceinline__ int swz(int row, int g) {
    return row * 128 + (((g ^ (row & 7)) & 7) << 4);
}

// ===========================================================================
// prep: pre-split weights into FRAGMENT-MAJOR image chunks in ws (unchanged).
// ===========================================================================
__global__ __launch_bounds__(384) void prep_kernel(
    const float* __restrict__ qkv_w, const float* __restrict__ proj_w,
    char* __restrict__ ws)
{
    const int b = blockIdx.x, row = threadIdx.x;
    float w; size_t base;
    int kl;
    if (b < 1152) {
        int s = b / 384, r = b % 384, ck = r / 32; kl = r % 32;
        w = qkv_w[(size_t)(ck * 32 + kl) * 1152 + s * 384 + row];
        base = WS_QKVB + (size_t)(s * 12 + ck) * 49152;
    } else {
        int b1 = b - 1152, ck = b1 / 32; kl = b1 % 32;
        w = proj_w[(size_t)(ck * 32 + kl) * 384 + row];
        base = WS_PROJB + (size_t)ck * 49152;
    }
    u16 h, l; split2(w, h, l);
    int o = ((row >> 4) * 4 + (kl >> 3)) * 256 + (row & 15) * 16 + (kl & 7) * 2;
    *(u16*)(ws + base + o)         = h;
    *(u16*)(ws + base + 24576 + o) = l;
}

// ===========================================================================
// QKV GEMM: BK=64, TWO windows (M=128), N=96 quarter-slab.
// block=512 (4M x 2N waves, 6 w/EU -> 3 blocks/CU); per chunk each wave does
// 36 MFMA (2 ks x 2 win x 3 frags x 3 terms) per ONE barrier; 6 chunks only.
// LDS: 2 x 24576 dbuf. grid = 512 pairs x 12 (s,qt) = 6144.
// ===========================================================================
__global__ __launch_bounds__(512, 6) void qkv_gemm_kernel(
    const float* __restrict__ x, const char* __restrict__ wsB,
    const float* __restrict__ qkv_b, char* __restrict__ ws)
{
    __shared__ __align__(16) char bt[49152];   // 2 buffers x 24576

    const int bid = blockIdx.x;
    const int nt = bid % 12, s = nt >> 2, qt = nt & 3;
    const int pair = bid / 12;
    const int tid = threadIdx.x, lane = tid & 63;
    const int wv = tid >> 6;
    const int wm = wv >> 1, wn = wv & 1;
    const int ln = lane & 15, kq = lane >> 4;

    const float* xr[2];
    #pragma unroll
    for (int am = 0; am < 2; ++am) {
        int wwin = pair * 2 + am;
        int bi = wwin >> 6, win = wwin & 63;
        int wy = win >> 3, wx = win & 7;
        int arow = wm * 16 + ln;
        int ar = (arow < 49) ? arow : 0;
        int Y = wy * 7 + ar / 7, X = wx * 7 + ar % 7;
        xr[am] = x + (size_t)((bi * 56 + Y) * 56 + X) * 384 + kq * 8;
    }
    const char* wB = wsB + WS_QKVB + (size_t)s * 12 * 49152;

    // stage one BK=64 chunk (two ck32 image chunks) into buf: 24 segs x 1024B.
    // seg sg = ks*12 + r: src = chunk(2*c64+ks) quarter qt, r<6 hi else lo;
    // dst = buf*24576 + sg*1024 (r>=6 maps to 6144+(r-6)*1024 = r*1024).
    auto stage = [&](int c64, int buf) {
        #pragma unroll
        for (int i = 0; i < 3; ++i) {
            int sg = wv + i * 8;            // 0..23
            int ks = sg / 12, r = sg % 12;
            const char* cb = wB + (size_t)(c64 * 2 + ks) * 49152 + (size_t)qt * 6144;
            const char* src = (r < 6) ? (cb + r * 1024)
                                      : (cb + 18432 + r * 1024);
            gload16(src + lane * 16, bt + buf * 24576 + sg * 1024);
        }
    };

    stage(0, 0);
    __syncthreads();

    f32x4 acc[2][3];
    #pragma unroll
    for (int am = 0; am < 2; ++am)
        #pragma unroll
        for (int f = 0; f < 3; ++f) { acc[am][f][0]=0.f; acc[am][f][1]=0.f; acc[am][f][2]=0.f; acc[am][f][3]=0.f; }

    #pragma unroll 1
    for (int c64 = 0; c64 < 6; ++c64) {
        const int cur = (c64 & 1) * 24576;
        if (c64 < 5) stage(c64 + 1, (c64 & 1) ^ 1);
        #pragma unroll
        for (int ks = 0; ks < 2; ++ks) {
            bf16x8 ah0, al0, ah1, al1;
            {
                float av[8];
                const float* xp = xr[0] + c64 * 64 + ks * 32;
                float4 a0 = *(const float4*)xp;
                float4 a1 = *(const float4*)(xp + 4);
                av[0]=a0.x; av[1]=a0.y; av[2]=a0.z; av[3]=a0.w;
                av[4]=a1.x; av[5]=a1.y; av[6]=a1.z; av[7]=a1.w;
                split8(av, ah0, al0);
                xp = xr[1] + c64 * 64 + ks * 32;
                a0 = *(const float4*)xp;
                a1 = *(const float4*)(xp + 4);
                av[0]=a0.x; av[1]=a0.y; av[2]=a0.z; av[3]=a0.w;
                av[4]=a1.x; av[5]=a1.y; av[6]=a1.z; av[7]=a1.w;
                split8(av, ah1, al1);
            }
            #pragma unroll
            for (int f = 0; f < 3; ++f) {
                int off = cur + ks * 12288 + ((wn * 3 + f) * 4 + kq) * 256 + ln * 16;
                bf16x8 bh = *(const bf16x8*)(bt + off);
                bf16x8 bl = *(const bf16x8*)(bt + off + 6144);
                acc[0][f] = __builtin_amdgcn_mfma_f32_16x16x32_bf16(ah0, bh, acc[0][f], 0, 0, 0);
                acc[0][f] = __builtin_amdgcn_mfma_f32_16x16x32_bf16(ah0, bl, acc[0][f], 0, 0, 0);
                acc[0][f] = __builtin_amdgcn_mfma_f32_16x16x32_bf16(al0, bh, acc[0][f], 0, 0, 0);
                acc[1][f] = __builtin_amdgcn_mfma_f32_16x16x32_bf16(ah1, bh, acc[1][f], 0, 0, 0);
                acc[1][f] = __builtin_amdgcn_mfma_f32_16x16x32_bf16(ah1, bl, acc[1][f], 0, 0, 0);
                acc[1][f] = __builtin_amdgcn_mfma_f32_16x16x32_bf16(al1, bh, acc[1][f], 0, 0, 0);
            }
        }
        __syncthreads();
    }

    // ---- epilogue: streaming writes into both windows' units ----
    #pragma unroll
    for (int am = 0; am < 2; ++am) {
        int wwin = pair * 2 + am;
        u16* ub = (u16*)(ws + WS_R0 + (size_t)(wwin * 12) * UNIT);
        #pragma unroll
        for (int f = 0; f < 3; ++f) {
            int n_local = qt * 96 + wn * 48 + f * 16 + ln;
            int hh = n_local >> 5, dd = n_local & 31;
            float bias = qkv_b[s * 384 + n_local];
            u16* u = ub + (size_t)hh * (UNIT / 2);
            #pragma unroll
            for (int r = 0; r < 4; ++r) {
                int wrow = wm * 16 + kq * 4 + r;
                if (wrow < 49) {
                    float val = acc[am][f][r] + bias;
                    if (s == 0) val *= SCALE;
                    u16 h, l; split2(val, h, l);
                    if (s == 0)      { u[wrow * 32 + dd] = h;        u[1568 + wrow * 32 + dd] = l; }
                    else if (s == 1) { u[3136 + wrow * 32 + dd] = h; u[4704 + wrow * 32 + dd] = l; }
                    else             { u[6272 + wrow * 32 + dd] = h; u[8320 + wrow * 32 + dd] = l; }
                }
            }
        }
    }
}

// ===========================================================================
// attention core: one block per GLOBAL window (256 thr = 4 waves). Unchanged.
// ===========================================================================
__global__ __launch_bounds__(256) void attn_core_kernel(
    const char* __restrict__ ws, const float* __restrict__ rel_table,
    float* __restrict__ out)
{
    __shared__ __align__(16) float pt[64][68];
    __shared__ __align__(16) float rel_all[2048];
    __shared__ float pmax[4][64];
    __shared__ float psum[4][64];
    __shared__ __align__(16) u16 vth[32][72];
    __shared__ __align__(16) u16 vtl[32][72];

    const int wi = blockIdx.x, bi = wi >> 6, win = wi & 63;
    const int wy = win >> 3, wx = win & 7;
    const int tid = threadIdx.x, lane = tid & 63, wv = tid >> 6;
    const int ln = lane & 15, kq = lane >> 4;

    for (int i = tid; i < 2028; i += 256) rel_all[i] = rel_table[i];
    for (int i = tid; i < 32 * 72; i += 256) { ((u16*)vth)[i] = 0; ((u16*)vtl)[i] = 0; }

    int m7[4], mr[4], outY[4], outX[4];
    bool mok[4];
    #pragma unroll
    for (int r = 0; r < 4; ++r) {
        int m = wv * 16 + kq * 4 + r;
        mok[r] = (m < 49);
        int a = mok[r] ? m : 0;
        m7[r] = a / 7; mr[r] = a % 7;
        outY[r] = wy * 7 + m7[r]; outX[r] = wx * 7 + mr[r];
    }
    int n7[4], nr[4];
    #pragma unroll
    for (int nt = 0; nt < 4; ++nt) {
        int n = nt * 16 + ln, a = (n < 49) ? n : 0;
        n7[nt] = a / 7; nr[nt] = a % 7;
    }
    const int mK = wv * 16 + ln;
    bf16x8 zz;
    #pragma unroll
    for (int j = 0; j < 8; ++j) zz[j] = 0;

    __syncthreads();

    for (int h = 0; h < NH; ++h) {
        const u16* u = (const u16*)(ws + WS_R0 + (size_t)(wi * 12 + h) * UNIT);
        const u16* qhi = u,        * qlo = u + 1568;
        const u16* khi = u + 3136, * klo = u + 4704;
        const u16* vhi = u + 6272, * vlo = u + 8320;

        if (tid < 196) {
            int row = tid >> 2, d0 = (tid & 3) * 8;
            bf16x8 v8h = *(const bf16x8*)(vhi + row * 32 + d0);
            bf16x8 v8l = *(const bf16x8*)(vlo + row * 32 + d0);
            #pragma unroll
            for (int j = 0; j < 8; ++j) {
                vth[d0 + j][row] = (u16)v8h[j];
                vtl[d0 + j][row] = (u16)v8l[j];
            }
        }

        bf16x8 kh = zz, kl = zz;
        if (mK < 49) {
            kh = *(const bf16x8*)(khi + mK * 32 + kq * 8);
            kl = *(const bf16x8*)(klo + mK * 32 + kq * 8);
        }
        f32x4 accs[4];
        #pragma unroll
        for (int nt = 0; nt < 4; ++nt) {
            int n = nt * 16 + ln;
            bf16x8 qh = zz, ql = zz;
            if (n < 49) {
                qh = *(const bf16x8*)(qhi + n * 32 + kq * 8);
                ql = *(const bf16x8*)(qlo + n * 32 + kq * 8);
            }
            f32x4 z; z[0]=0.f; z[1]=0.f; z[2]=0.f; z[3]=0.f;
            z = __builtin_amdgcn_mfma_f32_16x16x32_bf16(kh, qh, z, 0, 0, 0);
            z = __builtin_amdgcn_mfma_f32_16x16x32_bf16(kh, ql, z, 0, 0, 0);
            z = __builtin_amdgcn_mfma_f32_16x16x32_bf16(kl, qh, z, 0, 0, 0);
            accs[nt] = z;
        }

        float e[4][4], gmax[4], ginv[4];
        #pragma unroll
        for (int nt = 0; nt < 4; ++nt) {
            float lm = -3.4e38f;
            #pragma unroll
            for (int r = 0; r < 4; ++r) if (mok[r]) lm = fmaxf(lm, accs[nt][r]);
            lm = fmaxf(lm, __shfl_xor(lm, 16));
            lm = fmaxf(lm, __shfl_xor(lm, 32));
            if (kq == 0) pmax[wv][nt * 16 + ln] = lm;
        }
        __syncthreads();
        #pragma unroll
        for (int nt = 0; nt < 4; ++nt) {
            int n = nt * 16 + ln;
            gmax[nt] = fmaxf(fmaxf(pmax[0][n], pmax[1][n]), fmaxf(pmax[2][n], pmax[3][n]));
            float ls = 0.f;
            #pragma unroll
            for (int r = 0; r < 4; ++r) {
                e[nt][r] = mok[r] ? __expf(accs[nt][r] - gmax[nt]) : 0.f;
                ls += e[nt][r];
            }
            ls += __shfl_xor(ls, 16);
            ls += __shfl_xor(ls, 32);
            if (kq == 0) psum[wv][nt * 16 + ln] = ls;
        }
        __syncthreads();
        #pragma unroll
        for (int nt = 0; nt < 4; ++nt) {
            int n = nt * 16 + ln;
            ginv[nt] = 1.f / (psum[0][n] + psum[1][n] + psum[2][n] + psum[3][n]);
            #pragma unroll
            for (int r = 0; r < 4; ++r) {
                float val = 0.f;
                if (mok[r]) {
                    int bidx = (n7[nt] - m7[r] + 6) * 13 + (nr[nt] - mr[r] + 6);
                    val = e[nt][r] * ginv[nt] + rel_all[bidx * NH + h];
                }
                pt[n][wv * 16 + kq * 4 + r] = val;
            }
        }
        __syncthreads();

        bf16x8 pah[2], pal[2];
        #pragma unroll
        for (int mc = 0; mc < 2; ++mc) {
            const float* pp = &pt[wv * 16 + ln][mc * 32 + kq * 8];
            float v[8];
            float4 a0 = *(const float4*)pp;
            float4 a1 = *(const float4*)(pp + 4);
            v[0]=a0.x; v[1]=a0.y; v[2]=a0.z; v[3]=a0.w;
            v[4]=a1.x; v[5]=a1.y; v[6]=a1.z; v[7]=a1.w;
            split8(v, pah[mc], pal[mc]);
        }
        f32x4 acco[2];
        #pragma unroll
        for (int dt = 0; dt < 2; ++dt) { acco[dt][0]=0.f; acco[dt][1]=0.f; acco[dt][2]=0.f; acco[dt][3]=0.f; }
        #pragma unroll
        for (int dt = 0; dt < 2; ++dt) {
            int d = dt * 16 + ln;
            #pragma unroll
            for (int mc = 0; mc < 2; ++mc) {
                bf16x8 vh = *(const bf16x8*)(&vth[d][mc * 32 + kq * 8]);
                bf16x8 vl = *(const bf16x8*)(&vtl[d][mc * 32 + kq * 8]);
                acco[dt] = __builtin_amdgcn_mfma_f32_16x16x32_bf16(pah[mc], vh, acco[dt], 0, 0, 0);
                acco[dt] = __builtin_amdgcn_mfma_f32_16x16x32_bf16(pah[mc], vl, acco[dt], 0, 0, 0);
                acco[dt] = __builtin_amdgcn_mfma_f32_16x16x32_bf16(pal[mc], vh, acco[dt], 0, 0, 0);
            }
        }
        #pragma unroll
        for (int r = 0; r < 4; ++r) {
            if (mok[r]) {
                size_t base = (size_t)((bi * 56 + outY[r]) * 56 + outX[r]) * 384 + h * 32;
                out[base + ln]      = acco[0][r];
                out[base + 16 + ln] = acco[1][r];
            }
        }
        __syncthreads();
    }
}

// ===========================================================================
// proj: BK=32, reg-staged frag-major image, IN PLACE (R10-proven).
// ===========================================================================
__global__ __launch_bounds__(512) void proj_kernel(
    const char* __restrict__ wsB, const float* __restrict__ proj_b,
    float* __restrict__ out)
{
    __shared__ __align__(16) char bt[49152];

    const int tid = threadIdx.x, lane = tid & 63;
    const int wv = tid >> 6, wm = wv >> 1, wn = wv & 1;
    const int ln = lane & 15, kq = lane >> 4;
    const size_t tok0 = (size_t)blockIdx.x * 64;
    const float* xr = out + (tok0 + wm * 16 + ln) * 384 + kq * 8;
    const char* wB = wsB + WS_PROJB;

    bf16x8 st[6];
    #pragma unroll
    for (int i = 0; i < 6; ++i)
        st[i] = *(const bf16x8*)(wB + (size_t)tid * 16 + i * 8192);

    float4 a0 = *(const float4*)(xr);
    float4 a1 = *(const float4*)(xr + 4);

    f32x4 acc[12];
    #pragma unroll
    for (int f = 0; f < 12; ++f) { acc[f][0]=0.f; acc[f][1]=0.f; acc[f][2]=0.f; acc[f][3]=0.f; }

    #pragma unroll 1
    for (int ck = 0; ck < 12; ++ck) {
        __syncthreads();
        #pragma unroll
        for (int i = 0; i < 6; ++i)
            *(bf16x8*)(bt + tid * 16 + i * 8192) = st[i];
        __syncthreads();
        float4 na0, na1;
        if (ck < 11) {
            const char* nb = wB + (size_t)(ck + 1) * 49152;
            #pragma unroll
            for (int i = 0; i < 6; ++i)
                st[i] = *(const bf16x8*)(nb + (size_t)tid * 16 + i * 8192);
            na0 = *(const float4*)(xr + (ck + 1) * 32);
            na1 = *(const float4*)(xr + (ck + 1) * 32 + 4);
        }
        float av[8];
        av[0]=a0.x; av[1]=a0.y; av[2]=a0.z; av[3]=a0.w;
        av[4]=a1.x; av[5]=a1.y; av[6]=a1.z; av[7]=a1.w;
        bf16x8 ah, al; split8(av, ah, al);
        #pragma unroll
        for (int f = 0; f < 12; ++f) {
            int off = (wn * 12 + f) * 1024 + kq * 256 + ln * 16;
            bf16x8 bh = *(const bf16x8*)(bt + off);
            bf16x8 bl = *(const bf16x8*)(bt + 24576 + off);
            acc[f] = __builtin_amdgcn_mfma_f32_16x16x32_bf16(ah, bh, acc[f], 0, 0, 0);
            acc[f] = __builtin_amdgcn_mfma_f32_16x16x32_bf16(ah, bl, acc[f], 0, 0, 0);
            acc[f] = __builtin_amdgcn_mfma_f32_16x16x32_bf16(al, bh, acc[f], 0, 0, 0);
        }
        if (ck < 11) { a0 = na0; a1 = na1; }
    }
    __syncthreads();

    #pragma unroll
    for (int f = 0; f < 12; ++f) {
        int n = wn * 192 + f * 16 + ln;
        float pb = proj_b[n];
        #pragma unroll
        for (int r = 0; r < 4; ++r)
            out[(tok0 + wm * 16 + kq * 4 + r) * 384 + n] = acc[f][r] + pb;
    }
}

// ===========================================================================
// PATH B fallback (small ws): R4 fused per-window kernel + runtime-split proj.
// ===========================================================================
__global__ __launch_bounds__(512) void wmsa_attn_kernel(
    const float* __restrict__ x, const float* __restrict__ qkv_w,
    const float* __restrict__ qkv_b, const float* __restrict__ rel_table,
    float* __restrict__ out)
{
    __shared__ __align__(16) char smem[55936];
    u16* bt_hi = (u16*)smem;
    u16* bt_lo = (u16*)(smem + 24576);
    float* qs  = (float*)smem;
    float* kss = (float*)(smem + 14976);
    float* vst = (float*)(smem + 29952);
    float* at  = (float*)(smem + 44288);

    const int wi = blockIdx.x, bi = wi >> 6, win = wi & 63;
    const int wy = win >> 3, wx = win & 7;
    const int tid = threadIdx.x, lane = tid & 63;
    const int wv = tid >> 6, wm = wv >> 1, wn = wv & 1;
    const int ln = lane & 15, kq = lane >> 4;
    const int arow = wm * 16 + ln;

    int Y = wy * 7, X = wx * 7;
    if (arow < 49) { Y += arow / 7; X += arow % 7; }
    const float* xr = x + (size_t)((bi * 56 + Y) * 56 + X) * 384;

    int tcol[3], tkg[3];
    #pragma unroll
    for (int t = 0; t < 3; ++t) { int idx = tid + t * 512; tcol[t] = idx % 192; tkg[t] = idx / 192; }
    float rr[3][8];
    auto loadB = [&](int p, int ck) {
        #pragma unroll
        for (int t = 0; t < 3; ++t) {
            int c = tcol[t];
            int n = (c >> 6) * 384 + p * 64 + (c & 63);
            const float* wp = qkv_w + (size_t)(ck * 64 + tkg[t] * 8) * 1152 + n;
            #pragma unroll
            for (int j = 0; j < 8; ++j) rr[t][j] = wp[(size_t)j * 1152];
        }
    };
    loadB(0, 0);

    #pragma unroll 1
    for (int p = 0; p < 6; ++p) {
        f32x4 acc[6];
        #pragma unroll
        for (int f = 0; f < 6; ++f) { acc[f][0]=0.f; acc[f][1]=0.f; acc[f][2]=0.f; acc[f][3]=0.f; }
        #pragma unroll 1
        for (int ck = 0; ck < 6; ++ck) {
            __syncthreads();
            #pragma unroll
            for (int t = 0; t < 3; ++t) {
                bf16x8 h, l;
                split8(rr[t], h, l);
                *(bf16x8*)((char*)bt_hi + swz(tcol[t], tkg[t])) = h;
                *(bf16x8*)((char*)bt_lo + swz(tcol[t], tkg[t])) = l;
            }
            __syncthreads();
            if (ck < 5) loadB(p, ck + 1);
            else if (p < 5) loadB(p + 1, 0);
            #pragma unroll
            for (int ks = 0; ks < 2; ++ks) {
                float av[8];
                const float* xp = xr + ck * 64 + ks * 32 + kq * 8;
                float4 a0 = *(const float4*)xp;
                float4 a1 = *(const float4*)(xp + 4);
                av[0]=a0.x; av[1]=a0.y; av[2]=a0.z; av[3]=a0.w;
                av[4]=a1.x; av[5]=a1.y; av[6]=a1.z; av[7]=a1.w;
                bf16x8 ah, al; split8(av, ah, al);
                #pragma unroll
                for (int f = 0; f < 6; ++f) {
                    int n = wn * 96 + f * 16 + ln;
                    int off = swz(n, ks * 4 + kq);
                    bf16x8 bh = *(const bf16x8*)((char*)bt_hi + off);
                    bf16x8 bl = *(const bf16x8*)((char*)bt_lo + off);
                    acc[f] = __builtin_amdgcn_mfma_f32_16x16x32_bf16(ah, bh, acc[f], 0, 0, 0);
                    acc[f] = __builtin_amdgcn_mfma_f32_16x16x32_bf16(ah, bl, acc[f], 0, 0, 0);
                    acc[f] = __builtin_amdgcn_mfma_f32_16x16x32_bf16(al, bh, acc[f], 0, 0, 0);
                }
            }
        }
        __syncthreads();
        #pragma unroll
        for (int f = 0; f < 6; ++f) {
            int c = wn * 96 + f * 16 + ln;
            int m = c >> 6, d = c & 63, hh = d >> 5, dd = d & 31;
            float bias = qkv_b[m * 384 + p * 64 + d];
            #pragma unroll
            for (int r = 0; r < 4; ++r) {
                int row = wm * 16 + kq * 4 + r;
                if (row < 52) {
                    float val = acc[f][r] + bias;
                    if (m == 0)      qs [(hh * 52 + row) * 36 + dd] = val * SCALE;
                    else if (m == 1) kss[(hh * 52 + row) * 36 + dd] = val;
                    else             vst[(hh * 32 + dd) * 56 + row] = val;
                }
            }
        }
        __syncthreads();
        for (int hh = 0; hh < 2; ++hh) {
            const int h = p * 2 + hh;
            const float* qsh = qs  + hh * 52 * 36;
            const float* ksh = kss + hh * 52 * 36;
            const float* vsh = vst + hh * 32 * 56;
            if (tid < 169) {
                const int n0 = (tid / 13) * 4, m0 = (tid % 13) * 4;
                float s[4][4] = {};
                #pragma unroll
                for (int k = 0; k < 32; k += 4) {
                    float4 qa[4], kb[4];
                    #pragma unroll
                    for (int i = 0; i < 4; ++i) qa[i] = *(const float4*)&qsh[(n0 + i) * 36 + k];
                    #pragma unroll
                    for (int j = 0; j < 4; ++j) kb[j] = *(const float4*)&ksh[(m0 + j) * 36 + k];
                    #pragma unroll
                    for (int i = 0; i < 4; ++i)
                        #pragma unroll
                        for (int j = 0; j < 4; ++j)
                            s[i][j] += qa[i].x * kb[j].x + qa[i].y * kb[j].y +
                                       qa[i].z * kb[j].z + qa[i].w * kb[j].w;
                }
                #pragma unroll
                for (int i = 0; i < 4; ++i)
                    #pragma unroll
                    for (int j = 0; j < 4; ++j)
                        at[(n0 + i) * 56 + m0 + j] = s[i][j];
            }
            __syncthreads();
            for (int r = wv; r < 49; r += 8) {
                float v = (lane < 49) ? at[r * 56 + lane] : -3.4e38f;
                float mx = v;
                #pragma unroll
                for (int off = 32; off; off >>= 1) mx = fmaxf(mx, __shfl_xor(mx, off));
                float ex = (lane < 49) ? __expf(v - mx) : 0.f;
                float ssum = ex;
                #pragma unroll
                for (int off = 32; off; off >>= 1) ssum += __shfl_xor(ssum, off);
                if (lane < 52) {
                    float res = 0.f;
                    if (lane < 49) {
                        int py = r / 7, px = r % 7, qy = lane / 7, qx = lane % 7;
                        int bidx = (py - qy + 6) * 13 + (px - qx + 6);
                        res = ex / ssum + rel_table[bidx * NH + h];
                    }
                    at[r * 56 + lane] = res;
                }
            }
            __syncthreads();
            if (tid < 208) {
                const int n0 = (tid / 16) * 4, d0 = (tid % 16) * 2;
                float o[4][2] = {};
                #pragma unroll
                for (int m2 = 0; m2 < 52; m2 += 4) {
                    float4 pa[4], vb2[2];
                    #pragma unroll
                    for (int i = 0; i < 4; ++i) pa[i] = *(const float4*)&at[(n0 + i) * 56 + m2];
                    #pragma unroll
                    for (int j = 0; j < 2; ++j) vb2[j] = *(const float4*)&vsh[(d0 + j) * 56 + m2];
                    #pragma unroll
                    for (int i = 0; i < 4; ++i)
                        #pragma unroll
                        for (int j = 0; j < 2; ++j)
                            o[i][j] += pa[i].x * vb2[j].x + pa[i].y * vb2[j].y +
                                       pa[i].z * vb2[j].z + pa[i].w * vb2[j].w;
                }
                #pragma unroll
                for (int i = 0; i < 4; ++i) {
                    int n = n0 + i;
                    if (n < 49) {
                        int Yo = wy * 7 + n / 7, Xo = wx * 7 + n % 7;
                        size_t base = (size_t)((bi * 56 + Yo) * 56 + Xo) * 384 + h * 32 + d0;
                        *(float2*)(out + base) = make_float2(o[i][0], o[i][1]);
                    }
                }
            }
            __syncthreads();
        }
    }
}

__global__ __launch_bounds__(512) void wmsa_proj_kernel(
    const float* __restrict__ proj_w, const float* __restrict__ proj_b,
    float* __restrict__ out)
{
    __shared__ __align__(16) char smem[98304];
    u16* bt_hi = (u16*)smem;
    u16* bt_lo = (u16*)(smem + 49152);

    const int tid = threadIdx.x, lane = tid & 63;
    const int wv = tid >> 6, wm = wv >> 1, wn = wv & 1;
    const int ln = lane & 15, kq = lane >> 4;
    const size_t tok0 = (size_t)blockIdx.x * 64;
    const float* xr = out + (tok0 + wm * 16 + ln) * 384;

    int tcol[6], tkg[6];
    #pragma unroll
    for (int t = 0; t < 6; ++t) { int idx = tid + t * 512; tcol[t] = idx % 384; tkg[t] = idx / 384; }
    float rr[6][8];
    auto loadB = [&](int ck) {
        #pragma unroll
        for (int t = 0; t < 6; ++t) {
            const float* wp = proj_w + (size_t)(ck * 64 + tkg[t] * 8) * 384 + tcol[t];
            #pragma unroll
            for (int j = 0; j < 8; ++j) rr[t][j] = wp[(size_t)j * 384];
        }
    };
    loadB(0);

    f32x4 acc[12];
    #pragma unroll
    for (int f = 0; f < 12; ++f) { acc[f][0]=0.f; acc[f][1]=0.f; acc[f][2]=0.f; acc[f][3]=0.f; }

    #pragma unroll 1
    for (int ck = 0; ck < 6; ++ck) {
        __syncthreads();
        #pragma unroll
        for (int t = 0; t < 6; ++t) {
            bf16x8 h, l; split8(rr[t], h, l);
            *(bf16x8*)((char*)bt_hi + swz(tcol[t], tkg[t])) = h;
            *(bf16x8*)((char*)bt_lo + swz(tcol[t], tkg[t])) = l;
        }
        __syncthreads();
        if (ck < 5) loadB(ck + 1);
        #pragma unroll
        for (int ks = 0; ks < 2; ++ks) {
            float av[8];
            const float* xp = xr + ck * 64 + ks * 32 + kq * 8;
            float4 a0 = *(const float4*)xp;
            float4 a1 = *(const float4*)(xp + 4);
            av[0]=a0.x; av[1]=a0.y; av[2]=a0.z; av[3]=a0.w;
            av[4]=a1.x; av[5]=a1.y; av[6]=a1.z; av[7]=a1.w;
            bf16x8 ah, al; split8(av, ah, al);
            #pragma unroll
            for (int f = 0; f < 12; ++f) {
                int n = wn * 192 + f * 16 + ln;
                int off = swz(n, ks * 4 + kq);
                bf16x8 bh = *(const bf16x8*)((char*)bt_hi + off);
                bf16x8 bl = *(const bf16x8*)((char*)bt_lo + off);
                acc[f] = __builtin_amdgcn_mfma_f32_16x16x32_bf16(ah, bh, acc[f], 0, 0, 0);
                acc[f] = __builtin_amdgcn_mfma_f32_16x16x32_bf16(ah, bl, acc[f], 0, 0, 0);
                acc[f] = __builtin_amdgcn_mfma_f32_16x16x32_bf16(al, bh, acc[f], 0, 0, 0);
            }
        }
    }
    __syncthreads();

    #pragma unroll
    for (int f = 0; f < 12; ++f) {
        int n = wn * 192 + f * 16 + ln;
        float pb = proj_b[n];
        #pragma unroll
        for (int r = 0; r < 4; ++r)
            out[(tok0 + wm * 16 + kq * 4 + r) * 384 + n] = acc[f][r] + pb;
    }
}

extern "C" void kernel_launch(void* const* d_in, const int* in_sizes, int n_in,
                              void* d_out, int out_size, void* d_ws, size_t ws_size,
                              hipStream_t stream) {
    const float* x         = (const float*)d_in[0];
    const float* qkv_w     = (const float*)d_in[1];
    const float* qkv_b     = (const float*)d_in[2];
    const float* proj_w    = (const float*)d_in[3];
    const float* proj_b    = (const float*)d_in[4];
    const float* rel_table = (const float*)d_in[5];
    float* out = (float*)d_out;
    char* wsc = (char*)d_ws;

    if (ws_size >= WS_NEED) {
        hipLaunchKernelGGL(prep_kernel, dim3(1536), dim3(384), 0, stream,
                           qkv_w, proj_w, wsc);
        hipLaunchKernelGGL(qkv_gemm_kernel, dim3(6144), dim3(512), 0, stream,
                           x, wsc, qkv_b, wsc);
        hipLaunchKernelGGL(attn_core_kernel, dim3(1024), dim3(256), 0, stream,
                           wsc, rel_table, out);
        hipLaunchKernelGGL(proj_kernel, dim3(784), dim3(512), 0, stream,
                           wsc, proj_b, out);
    } else {
        hipLaunchKernelGGL(wmsa_attn_kernel, dim3(1024), dim3(512), 0, stream,
                           x, qkv_w, qkv_b, rel_table, out);
        hipLaunchKernelGGL(wmsa_proj_kernel, dim3(784), dim3(512), 0, stream,
                           proj_w, proj_b, out);
    }
}

// Round 19
// 429.423 us; speedup vs baseline: 1.1530x; 1.1530x over previous
//
#include <hip/hip_runtime.h>
#include <hip/hip_bf16.h>

typedef unsigned short u16;
typedef __attribute__((ext_vector_type(8))) short bf16x8;
typedef __attribute__((ext_vector_type(4))) float f32x4;

#define NH 12
#define SCALE 0.1767766952966369f

// ---- ws layout (bytes) ----
#define UNIT 20992
#define WS_R0    ((size_t)0)
#define WS_QKVB  ((size_t)12288 * UNIT)                 // 257,949,696
#define WS_PROJB (WS_QKVB + (size_t)3 * 12 * 49152)     // +1,769,472
#define WS_NEED  (WS_PROJB + (size_t)12 * 49152)        // = 260,308,992

// split fp32 -> bf16 hi/lo via native RNE casts
__device__ __forceinline__ void split2(float x, u16& h, u16& l) {
    __hip_bfloat16 hb = __float2bfloat16(x);
    float hf = __bfloat162float(hb);
    __hip_bfloat16 lb = __float2bfloat16(x - hf);
    h = __bfloat16_as_ushort(hb);
    l = __bfloat16_as_ushort(lb);
}
__device__ __forceinline__ void split8(const float* v, bf16x8& hi, bf16x8& lo) {
    #pragma unroll
    for (int j = 0; j < 8; ++j) {
        u16 h, l; split2(v[j], h, l);
        hi[j] = (short)h; lo[j] = (short)l;
    }
}

// async global->LDS, 16B per lane
__device__ __forceinline__ void gload16(const char* g, char* l) {
    __builtin_amdgcn_global_load_lds(
        (const __attribute__((address_space(1))) unsigned*)g,
        (__attribute__((address_space(3))) unsigned*)l, 16, 0, 0);
}

// fallback-path swizzle
__device__ __forceinline__ int swz(int row, int g) {
    return row * 128 + (((g ^ (row & 7)) & 7) << 4);
}

// ===========================================================================
// prep: pre-split weights into FRAGMENT-MAJOR image chunks in ws (unchanged).
// ===========================================================================
__global__ __launch_bounds__(384) void prep_kernel(
    const float* __restrict__ qkv_w, const float* __restrict__ proj_w,
    char* __restrict__ ws)
{
    const int b = blockIdx.x, row = threadIdx.x;
    float w; size_t base;
    int kl;
    if (b < 1152) {
        int s = b / 384, r = b % 384, ck = r / 32; kl = r % 32;
        w = qkv_w[(size_t)(ck * 32 + kl) * 1152 + s * 384 + row];
        base = WS_QKVB + (size_t)(s * 12 + ck) * 49152;
    } else {
        int b1 = b - 1152, ck = b1 / 32; kl = b1 % 32;
        w = proj_w[(size_t)(ck * 32 + kl) * 384 + row];
        base = WS_PROJB + (size_t)ck * 49152;
    }
    u16 h, l; split2(w, h, l);
    int o = ((row >> 4) * 4 + (kl >> 3)) * 256 + (row & 15) * 16 + (kl & 7) * 2;
    *(u16*)(ws + base + o)         = h;
    *(u16*)(ws + base + 24576 + o) = l;
}

// ===========================================================================
// QKV GEMM: R16 tile (TWO windows M=128 x N=192, BK=32) + T4 counted-vmcnt
// raw barriers (loads stay in flight across barriers; never drain mid-loop).
// block=512 (4M x 2N waves, 2 blocks/CU). grid = 512 pairs x 6 (s,lt) = 3072.
// ===========================================================================
__global__ __launch_bounds__(512, 4) void qkv_gemm_kernel(
    const float* __restrict__ x, const char* __restrict__ wsB,
    const float* __restrict__ qkv_b, char* __restrict__ ws)
{
    __shared__ __align__(16) char bt[49152];   // 2 buffers x 24576

    const int bid = blockIdx.x;
    const int nt = bid % 6, s = nt >> 1, lt = nt & 1;
    const int pair = bid / 6;
    const int tid = threadIdx.x, lane = tid & 63;
    const int wv = tid >> 6;
    const int wm = wv >> 1, wn = wv & 1;
    const int ln = lane & 15, kq = lane >> 4;

    const float* xr[2];
    #pragma unroll
    for (int am = 0; am < 2; ++am) {
        int wwin = pair * 2 + am;
        int bi = wwin >> 6, win = wwin & 63;
        int wy = win >> 3, wx = win & 7;
        int arow = wm * 16 + ln;
        int ar = (arow < 49) ? arow : 0;
        int Y = wy * 7 + ar / 7, X = wx * 7 + ar % 7;
        xr[am] = x + (size_t)((bi * 56 + Y) * 56 + X) * 384 + kq * 8;
    }
    const char* wB = wsB + WS_QKVB + (size_t)s * 12 * 49152;

    // 24 segs x 1024 B per chunk; each wave issues 3 gload16
    auto stage = [&](int ck, int buf) {
        const char* cb = wB + (size_t)ck * 49152 + (size_t)lt * 12288;
        #pragma unroll
        for (int i = 0; i < 3; ++i) {
            int seg = wv + i * 8;
            const char* src = (seg < 12) ? (cb + seg * 1024)
                                         : (cb + 24576 + (seg - 12) * 1024);
            gload16(src + lane * 16, bt + buf * 24576 + seg * 1024);
        }
    };

    // prologue: stage chunk0 (3 loads) + A chunk0 prefetch (4 loads)
    stage(0, 0);
    float4 a0A = *(const float4*)(xr[0]);
    float4 a1A = *(const float4*)(xr[0] + 4);
    float4 a0B = *(const float4*)(xr[1]);
    float4 a1B = *(const float4*)(xr[1] + 4);

    f32x4 acc[2][6];
    #pragma unroll
    for (int am = 0; am < 2; ++am)
        #pragma unroll
        for (int f = 0; f < 6; ++f) { acc[am][f][0]=0.f; acc[am][f][1]=0.f; acc[am][f][2]=0.f; acc[am][f][3]=0.f; }

    #pragma unroll 1
    for (int ck = 0; ck < 12; ++ck) {
        const int cur = (ck & 1) * 24576;
        float4 n0A, n1A, n0B, n1B;
        if (ck < 11) {
            stage(ck + 1, (ck & 1) ^ 1);               // 3 loads, other buf
            n0A = *(const float4*)(xr[0] + (ck + 1) * 32);   // 4 loads
            n1A = *(const float4*)(xr[0] + (ck + 1) * 32 + 4);
            n0B = *(const float4*)(xr[1] + (ck + 1) * 32);
            n1B = *(const float4*)(xr[1] + (ck + 1) * 32 + 4);
            // wait: all loads OLDER than the 7 just issued (i.e. cur's stage
            // + current A raws) retired; next chunk's 7 stay in flight.
            asm volatile("s_waitcnt vmcnt(7)" ::: "memory");
        } else {
            asm volatile("s_waitcnt vmcnt(0)" ::: "memory");
        }
        __builtin_amdgcn_s_barrier();                  // all waves' cur loads done
        __builtin_amdgcn_sched_barrier(0);             // pin: no ds_read hoist

        bf16x8 ah0, al0, ah1, al1;
        {
            float av[8];
            av[0]=a0A.x; av[1]=a0A.y; av[2]=a0A.z; av[3]=a0A.w;
            av[4]=a1A.x; av[5]=a1A.y; av[6]=a1A.z; av[7]=a1A.w;
            split8(av, ah0, al0);
            av[0]=a0B.x; av[1]=a0B.y; av[2]=a0B.z; av[3]=a0B.w;
            av[4]=a1B.x; av[5]=a1B.y; av[6]=a1B.z; av[7]=a1B.w;
            split8(av, ah1, al1);
        }
        #pragma unroll
        for (int f = 0; f < 6; ++f) {
            int off = cur + ((wn * 6 + f) * 4 + kq) * 256 + ln * 16;
            bf16x8 bh = *(const bf16x8*)(bt + off);
            bf16x8 bl = *(const bf16x8*)(bt + off + 12288);
            acc[0][f] = __builtin_amdgcn_mfma_f32_16x16x32_bf16(ah0, bh, acc[0][f], 0, 0, 0);
            acc[0][f] = __builtin_amdgcn_mfma_f32_16x16x32_bf16(ah0, bl, acc[0][f], 0, 0, 0);
            acc[0][f] = __builtin_amdgcn_mfma_f32_16x16x32_bf16(al0, bh, acc[0][f], 0, 0, 0);
            acc[1][f] = __builtin_amdgcn_mfma_f32_16x16x32_bf16(ah1, bh, acc[1][f], 0, 0, 0);
            acc[1][f] = __builtin_amdgcn_mfma_f32_16x16x32_bf16(ah1, bl, acc[1][f], 0, 0, 0);
            acc[1][f] = __builtin_amdgcn_mfma_f32_16x16x32_bf16(al1, bh, acc[1][f], 0, 0, 0);
        }
        __builtin_amdgcn_sched_barrier(0);
        __builtin_amdgcn_s_barrier();                  // cur reads done before
                                                       // next iter overwrites
        if (ck < 11) { a0A = n0A; a1A = n1A; a0B = n0B; a1B = n1B; }
    }

    // ---- epilogue: streaming writes into both windows' units ----
    #pragma unroll
    for (int am = 0; am < 2; ++am) {
        int wwin = pair * 2 + am;
        u16* ub = (u16*)(ws + WS_R0 + (size_t)(wwin * 12) * UNIT);
        #pragma unroll
        for (int f = 0; f < 6; ++f) {
            int n_local = lt * 192 + wn * 96 + f * 16 + ln;
            int hh = n_local >> 5, dd = n_local & 31;
            float bias = qkv_b[s * 384 + n_local];
            u16* u = ub + (size_t)hh * (UNIT / 2);
            #pragma unroll
            for (int r = 0; r < 4; ++r) {
                int wrow = wm * 16 + kq * 4 + r;
                if (wrow < 49) {
                    float val = acc[am][f][r] + bias;
                    if (s == 0) val *= SCALE;
                    u16 h, l; split2(val, h, l);
                    if (s == 0)      { u[wrow * 32 + dd] = h;        u[1568 + wrow * 32 + dd] = l; }
                    else if (s == 1) { u[3136 + wrow * 32 + dd] = h; u[4704 + wrow * 32 + dd] = l; }
                    else             { u[6272 + wrow * 32 + dd] = h; u[8320 + wrow * 32 + dd] = l; }
                }
            }
        }
    }
}

// ===========================================================================
// attention core: one block per GLOBAL window (256 thr = 4 waves). Unchanged.
// ===========================================================================
__global__ __launch_bounds__(256) void attn_core_kernel(
    const char* __restrict__ ws, const float* __restrict__ rel_table,
    float* __restrict__ out)
{
    __shared__ __align__(16) float pt[64][68];
    __shared__ __align__(16) float rel_all[2048];
    __shared__ float pmax[4][64];
    __shared__ float psum[4][64];
    __shared__ __align__(16) u16 vth[32][72];
    __shared__ __align__(16) u16 vtl[32][72];

    const int wi = blockIdx.x, bi = wi >> 6, win = wi & 63;
    const int wy = win >> 3, wx = win & 7;
    const int tid = threadIdx.x, lane = tid & 63, wv = tid >> 6;
    const int ln = lane & 15, kq = lane >> 4;

    for (int i = tid; i < 2028; i += 256) rel_all[i] = rel_table[i];
    for (int i = tid; i < 32 * 72; i += 256) { ((u16*)vth)[i] = 0; ((u16*)vtl)[i] = 0; }

    int m7[4], mr[4], outY[4], outX[4];
    bool mok[4];
    #pragma unroll
    for (int r = 0; r < 4; ++r) {
        int m = wv * 16 + kq * 4 + r;
        mok[r] = (m < 49);
        int a = mok[r] ? m : 0;
        m7[r] = a / 7; mr[r] = a % 7;
        outY[r] = wy * 7 + m7[r]; outX[r] = wx * 7 + mr[r];
    }
    int n7[4], nr[4];
    #pragma unroll
    for (int nt = 0; nt < 4; ++nt) {
        int n = nt * 16 + ln, a = (n < 49) ? n : 0;
        n7[nt] = a / 7; nr[nt] = a % 7;
    }
    const int mK = wv * 16 + ln;
    bf16x8 zz;
    #pragma unroll
    for (int j = 0; j < 8; ++j) zz[j] = 0;

    __syncthreads();

    for (int h = 0; h < NH; ++h) {
        const u16* u = (const u16*)(ws + WS_R0 + (size_t)(wi * 12 + h) * UNIT);
        const u16* qhi = u,        * qlo = u + 1568;
        const u16* khi = u + 3136, * klo = u + 4704;
        const u16* vhi = u + 6272, * vlo = u + 8320;

        if (tid < 196) {
            int row = tid >> 2, d0 = (tid & 3) * 8;
            bf16x8 v8h = *(const bf16x8*)(vhi + row * 32 + d0);
            bf16x8 v8l = *(const bf16x8*)(vlo + row * 32 + d0);
            #pragma unroll
            for (int j = 0; j < 8; ++j) {
                vth[d0 + j][row] = (u16)v8h[j];
                vtl[d0 + j][row] = (u16)v8l[j];
            }
        }

        bf16x8 kh = zz, kl = zz;
        if (mK < 49) {
            kh = *(const bf16x8*)(khi + mK * 32 + kq * 8);
            kl = *(const bf16x8*)(klo + mK * 32 + kq * 8);
        }
        f32x4 accs[4];
        #pragma unroll
        for (int nt = 0; nt < 4; ++nt) {
            int n = nt * 16 + ln;
            bf16x8 qh = zz, ql = zz;
            if (n < 49) {
                qh = *(const bf16x8*)(qhi + n * 32 + kq * 8);
                ql = *(const bf16x8*)(qlo + n * 32 + kq * 8);
            }
            f32x4 z; z[0]=0.f; z[1]=0.f; z[2]=0.f; z[3]=0.f;
            z = __builtin_amdgcn_mfma_f32_16x16x32_bf16(kh, qh, z, 0, 0, 0);
            z = __builtin_amdgcn_mfma_f32_16x16x32_bf16(kh, ql, z, 0, 0, 0);
            z = __builtin_amdgcn_mfma_f32_16x16x32_bf16(kl, qh, z, 0, 0, 0);
            accs[nt] = z;
        }

        float e[4][4], gmax[4], ginv[4];
        #pragma unroll
        for (int nt = 0; nt < 4; ++nt) {
            float lm = -3.4e38f;
            #pragma unroll
            for (int r = 0; r < 4; ++r) if (mok[r]) lm = fmaxf(lm, accs[nt][r]);
            lm = fmaxf(lm, __shfl_xor(lm, 16));
            lm = fmaxf(lm, __shfl_xor(lm, 32));
            if (kq == 0) pmax[wv][nt * 16 + ln] = lm;
        }
        __syncthreads();
        #pragma unroll
        for (int nt = 0; nt < 4; ++nt) {
            int n = nt * 16 + ln;
            gmax[nt] = fmaxf(fmaxf(pmax[0][n], pmax[1][n]), fmaxf(pmax[2][n], pmax[3][n]));
            float ls = 0.f;
            #pragma unroll
            for (int r = 0; r < 4; ++r) {
                e[nt][r] = mok[r] ? __expf(accs[nt][r] - gmax[nt]) : 0.f;
                ls += e[nt][r];
            }
            ls += __shfl_xor(ls, 16);
            ls += __shfl_xor(ls, 32);
            if (kq == 0) psum[wv][nt * 16 + ln] = ls;
        }
        __syncthreads();
        #pragma unroll
        for (int nt = 0; nt < 4; ++nt) {
            int n = nt * 16 + ln;
            ginv[nt] = 1.f / (psum[0][n] + psum[1][n] + psum[2][n] + psum[3][n]);
            #pragma unroll
            for (int r = 0; r < 4; ++r) {
                float val = 0.f;
                if (mok[r]) {
                    int bidx = (n7[nt] - m7[r] + 6) * 13 + (nr[nt] - mr[r] + 6);
                    val = e[nt][r] * ginv[nt] + rel_all[bidx * NH + h];
                }
                pt[n][wv * 16 + kq * 4 + r] = val;
            }
        }
        __syncthreads();

        bf16x8 pah[2], pal[2];
        #pragma unroll
        for (int mc = 0; mc < 2; ++mc) {
            const float* pp = &pt[wv * 16 + ln][mc * 32 + kq * 8];
            float v[8];
            float4 a0 = *(const float4*)pp;
            float4 a1 = *(const float4*)(pp + 4);
            v[0]=a0.x; v[1]=a0.y; v[2]=a0.z; v[3]=a0.w;
            v[4]=a1.x; v[5]=a1.y; v[6]=a1.z; v[7]=a1.w;
            split8(v, pah[mc], pal[mc]);
        }
        f32x4 acco[2];
        #pragma unroll
        for (int dt = 0; dt < 2; ++dt) { acco[dt][0]=0.f; acco[dt][1]=0.f; acco[dt][2]=0.f; acco[dt][3]=0.f; }
        #pragma unroll
        for (int dt = 0; dt < 2; ++dt) {
            int d = dt * 16 + ln;
            #pragma unroll
            for (int mc = 0; mc < 2; ++mc) {
                bf16x8 vh = *(const bf16x8*)(&vth[d][mc * 32 + kq * 8]);
                bf16x8 vl = *(const bf16x8*)(&vtl[d][mc * 32 + kq * 8]);
                acco[dt] = __builtin_amdgcn_mfma_f32_16x16x32_bf16(pah[mc], vh, acco[dt], 0, 0, 0);
                acco[dt] = __builtin_amdgcn_mfma_f32_16x16x32_bf16(pah[mc], vl, acco[dt], 0, 0, 0);
                acco[dt] = __builtin_amdgcn_mfma_f32_16x16x32_bf16(pal[mc], vh, acco[dt], 0, 0, 0);
            }
        }
        #pragma unroll
        for (int r = 0; r < 4; ++r) {
            if (mok[r]) {
                size_t base = (size_t)((bi * 56 + outY[r]) * 56 + outX[r]) * 384 + h * 32;
                out[base + ln]      = acco[0][r];
                out[base + 16 + ln] = acco[1][r];
            }
        }
        __syncthreads();
    }
}

// ===========================================================================
// proj: BK=32, reg-staged frag-major image, IN PLACE (R10-proven).
// ===========================================================================
__global__ __launch_bounds__(512) void proj_kernel(
    const char* __restrict__ wsB, const float* __restrict__ proj_b,
    float* __restrict__ out)
{
    __shared__ __align__(16) char bt[49152];

    const int tid = threadIdx.x, lane = tid & 63;
    const int wv = tid >> 6, wm = wv >> 1, wn = wv & 1;
    const int ln = lane & 15, kq = lane >> 4;
    const size_t tok0 = (size_t)blockIdx.x * 64;
    const float* xr = out + (tok0 + wm * 16 + ln) * 384 + kq * 8;
    const char* wB = wsB + WS_PROJB;

    bf16x8 st[6];
    #pragma unroll
    for (int i = 0; i < 6; ++i)
        st[i] = *(const bf16x8*)(wB + (size_t)tid * 16 + i * 8192);

    float4 a0 = *(const float4*)(xr);
    float4 a1 = *(const float4*)(xr + 4);

    f32x4 acc[12];
    #pragma unroll
    for (int f = 0; f < 12; ++f) { acc[f][0]=0.f; acc[f][1]=0.f; acc[f][2]=0.f; acc[f][3]=0.f; }

    #pragma unroll 1
    for (int ck = 0; ck < 12; ++ck) {
        __syncthreads();
        #pragma unroll
        for (int i = 0; i < 6; ++i)
            *(bf16x8*)(bt + tid * 16 + i * 8192) = st[i];
        __syncthreads();
        float4 na0, na1;
        if (ck < 11) {
            const char* nb = wB + (size_t)(ck + 1) * 49152;
            #pragma unroll
            for (int i = 0; i < 6; ++i)
                st[i] = *(const bf16x8*)(nb + (size_t)tid * 16 + i * 8192);
            na0 = *(const float4*)(xr + (ck + 1) * 32);
            na1 = *(const float4*)(xr + (ck + 1) * 32 + 4);
        }
        float av[8];
        av[0]=a0.x; av[1]=a0.y; av[2]=a0.z; av[3]=a0.w;
        av[4]=a1.x; av[5]=a1.y; av[6]=a1.z; av[7]=a1.w;
        bf16x8 ah, al; split8(av, ah, al);
        #pragma unroll
        for (int f = 0; f < 12; ++f) {
            int off = (wn * 12 + f) * 1024 + kq * 256 + ln * 16;
            bf16x8 bh = *(const bf16x8*)(bt + off);
            bf16x8 bl = *(const bf16x8*)(bt + 24576 + off);
            acc[f] = __builtin_amdgcn_mfma_f32_16x16x32_bf16(ah, bh, acc[f], 0, 0, 0);
            acc[f] = __builtin_amdgcn_mfma_f32_16x16x32_bf16(ah, bl, acc[f], 0, 0, 0);
            acc[f] = __builtin_amdgcn_mfma_f32_16x16x32_bf16(al, bh, acc[f], 0, 0, 0);
        }
        if (ck < 11) { a0 = na0; a1 = na1; }
    }
    __syncthreads();

    #pragma unroll
    for (int f = 0; f < 12; ++f) {
        int n = wn * 192 + f * 16 + ln;
        float pb = proj_b[n];
        #pragma unroll
        for (int r = 0; r < 4; ++r)
            out[(tok0 + wm * 16 + kq * 4 + r) * 384 + n] = acc[f][r] + pb;
    }
}

// ===========================================================================
// PATH B fallback (small ws): R4 fused per-window kernel + runtime-split proj.
// ===========================================================================
__global__ __launch_bounds__(512) void wmsa_attn_kernel(
    const float* __restrict__ x, const float* __restrict__ qkv_w,
    const float* __restrict__ qkv_b, const float* __restrict__ rel_table,
    float* __restrict__ out)
{
    __shared__ __align__(16) char smem[55936];
    u16* bt_hi = (u16*)smem;
    u16* bt_lo = (u16*)(smem + 24576);
    float* qs  = (float*)smem;
    float* kss = (float*)(smem + 14976);
    float* vst = (float*)(smem + 29952);
    float* at  = (float*)(smem + 44288);

    const int wi = blockIdx.x, bi = wi >> 6, win = wi & 63;
    const int wy = win >> 3, wx = win & 7;
    const int tid = threadIdx.x, lane = tid & 63;
    const int wv = tid >> 6, wm = wv >> 1, wn = wv & 1;
    const int ln = lane & 15, kq = lane >> 4;
    const int arow = wm * 16 + ln;

    int Y = wy * 7, X = wx * 7;
    if (arow < 49) { Y += arow / 7; X += arow % 7; }
    const float* xr = x + (size_t)((bi * 56 + Y) * 56 + X) * 384;

    int tcol[3], tkg[3];
    #pragma unroll
    for (int t = 0; t < 3; ++t) { int idx = tid + t * 512; tcol[t] = idx % 192; tkg[t] = idx / 192; }
    float rr[3][8];
    auto loadB = [&](int p, int ck) {
        #pragma unroll
        for (int t = 0; t < 3; ++t) {
            int c = tcol[t];
            int n = (c >> 6) * 384 + p * 64 + (c & 63);
            const float* wp = qkv_w + (size_t)(ck * 64 + tkg[t] * 8) * 1152 + n;
            #pragma unroll
            for (int j = 0; j < 8; ++j) rr[t][j] = wp[(size_t)j * 1152];
        }
    };
    loadB(0, 0);

    #pragma unroll 1
    for (int p = 0; p < 6; ++p) {
        f32x4 acc[6];
        #pragma unroll
        for (int f = 0; f < 6; ++f) { acc[f][0]=0.f; acc[f][1]=0.f; acc[f][2]=0.f; acc[f][3]=0.f; }
        #pragma unroll 1
        for (int ck = 0; ck < 6; ++ck) {
            __syncthreads();
            #pragma unroll
            for (int t = 0; t < 3; ++t) {
                bf16x8 h, l;
                split8(rr[t], h, l);
                *(bf16x8*)((char*)bt_hi + swz(tcol[t], tkg[t])) = h;
                *(bf16x8*)((char*)bt_lo + swz(tcol[t], tkg[t])) = l;
            }
            __syncthreads();
            if (ck < 5) loadB(p, ck + 1);
            else if (p < 5) loadB(p + 1, 0);
            #pragma unroll
            for (int ks = 0; ks < 2; ++ks) {
                float av[8];
                const float* xp = xr + ck * 64 + ks * 32 + kq * 8;
                float4 a0 = *(const float4*)xp;
                float4 a1 = *(const float4*)(xp + 4);
                av[0]=a0.x; av[1]=a0.y; av[2]=a0.z; av[3]=a0.w;
                av[4]=a1.x; av[5]=a1.y; av[6]=a1.z; av[7]=a1.w;
                bf16x8 ah, al; split8(av, ah, al);
                #pragma unroll
                for (int f = 0; f < 6; ++f) {
                    int n = wn * 96 + f * 16 + ln;
                    int off = swz(n, ks * 4 + kq);
                    bf16x8 bh = *(const bf16x8*)((char*)bt_hi + off);
                    bf16x8 bl = *(const bf16x8*)((char*)bt_lo + off);
                    acc[f] = __builtin_amdgcn_mfma_f32_16x16x32_bf16(ah, bh, acc[f], 0, 0, 0);
                    acc[f] = __builtin_amdgcn_mfma_f32_16x16x32_bf16(ah, bl, acc[f], 0, 0, 0);
                    acc[f] = __builtin_amdgcn_mfma_f32_16x16x32_bf16(al, bh, acc[f], 0, 0, 0);
                }
            }
        }
        __syncthreads();
        #pragma unroll
        for (int f = 0; f < 6; ++f) {
            int c = wn * 96 + f * 16 + ln;
            int m = c >> 6, d = c & 63, hh = d >> 5, dd = d & 31;
            float bias = qkv_b[m * 384 + p * 64 + d];
            #pragma unroll
            for (int r = 0; r < 4; ++r) {
                int row = wm * 16 + kq * 4 + r;
                if (row < 52) {
                    float val = acc[f][r] + bias;
                    if (m == 0)      qs [(hh * 52 + row) * 36 + dd] = val * SCALE;
                    else if (m == 1) kss[(hh * 52 + row) * 36 + dd] = val;
                    else             vst[(hh * 32 + dd) * 56 + row] = val;
                }
            }
        }
        __syncthreads();
        for (int hh = 0; hh < 2; ++hh) {
            const int h = p * 2 + hh;
            const float* qsh = qs  + hh * 52 * 36;
            const float* ksh = kss + hh * 52 * 36;
            const float* vsh = vst + hh * 32 * 56;
            if (tid < 169) {
                const int n0 = (tid / 13) * 4, m0 = (tid % 13) * 4;
                float s[4][4] = {};
                #pragma unroll
                for (int k = 0; k < 32; k += 4) {
                    float4 qa[4], kb[4];
                    #pragma unroll
                    for (int i = 0; i < 4; ++i) qa[i] = *(const float4*)&qsh[(n0 + i) * 36 + k];
                    #pragma unroll
                    for (int j = 0; j < 4; ++j) kb[j] = *(const float4*)&ksh[(m0 + j) * 36 + k];
                    #pragma unroll
                    for (int i = 0; i < 4; ++i)
                        #pragma unroll
                        for (int j = 0; j < 4; ++j)
                            s[i][j] += qa[i].x * kb[j].x + qa[i].y * kb[j].y +
                                       qa[i].z * kb[j].z + qa[i].w * kb[j].w;
                }
                #pragma unroll
                for (int i = 0; i < 4; ++i)
                    #pragma unroll
                    for (int j = 0; j < 4; ++j)
                        at[(n0 + i) * 56 + m0 + j] = s[i][j];
            }
            __syncthreads();
            for (int r = wv; r < 49; r += 8) {
                float v = (lane < 49) ? at[r * 56 + lane] : -3.4e38f;
                float mx = v;
                #pragma unroll
                for (int off = 32; off; off >>= 1) mx = fmaxf(mx, __shfl_xor(mx, off));
                float ex = (lane < 49) ? __expf(v - mx) : 0.f;
                float ssum = ex;
                #pragma unroll
                for (int off = 32; off; off >>= 1) ssum += __shfl_xor(ssum, off);
                if (lane < 52) {
                    float res = 0.f;
                    if (lane < 49) {
                        int py = r / 7, px = r % 7, qy = lane / 7, qx = lane % 7;
                        int bidx = (py - qy + 6) * 13 + (px - qx + 6);
                        res = ex / ssum + rel_table[bidx * NH + h];
                    }
                    at[r * 56 + lane] = res;
                }
            }
            __syncthreads();
            if (tid < 208) {
                const int n0 = (tid / 16) * 4, d0 = (tid % 16) * 2;
                float o[4][2] = {};
                #pragma unroll
                for (int m2 = 0; m2 < 52; m2 += 4) {
                    float4 pa[4], vb2[2];
                    #pragma unroll
                    for (int i = 0; i < 4; ++i) pa[i] = *(const float4*)&at[(n0 + i) * 56 + m2];
                    #pragma unroll
                    for (int j = 0; j < 2; ++j) vb2[j] = *(const float4*)&vsh[(d0 + j) * 56 + m2];
                    #pragma unroll
                    for (int i = 0; i < 4; ++i)
                        #pragma unroll
                        for (int j = 0; j < 2; ++j)
                            o[i][j] += pa[i].x * vb2[j].x + pa[i].y * vb2[j].y +
                                       pa[i].z * vb2[j].z + pa[i].w * vb2[j].w;
                }
                #pragma unroll
                for (int i = 0; i < 4; ++i) {
                    int n = n0 + i;
                    if (n < 49) {
                        int Yo = wy * 7 + n / 7, Xo = wx * 7 + n % 7;
                        size_t base = (size_t)((bi * 56 + Yo) * 56 + Xo) * 384 + h * 32 + d0;
                        *(float2*)(out + base) = make_float2(o[i][0], o[i][1]);
                    }
                }
            }
            __syncthreads();
        }
    }
}

__global__ __launch_bounds__(512) void wmsa_proj_kernel(
    const float* __restrict__ proj_w, const float* __restrict__ proj_b,
    float* __restrict__ out)
{
    __shared__ __align__(16) char smem[98304];
    u16* bt_hi = (u16*)smem;
    u16* bt_lo = (u16*)(smem + 49152);

    const int tid = threadIdx.x, lane = tid & 63;
    const int wv = tid >> 6, wm = wv >> 1, wn = wv & 1;
    const int ln = lane & 15, kq = lane >> 4;
    const size_t tok0 = (size_t)blockIdx.x * 64;
    const float* xr = out + (tok0 + wm * 16 + ln) * 384;

    int tcol[6], tkg[6];
    #pragma unroll
    for (int t = 0; t < 6; ++t) { int idx = tid + t * 512; tcol[t] = idx % 384; tkg[t] = idx / 384; }
    float rr[6][8];
    auto loadB = [&](int ck) {
        #pragma unroll
        for (int t = 0; t < 6; ++t) {
            const float* wp = proj_w + (size_t)(ck * 64 + tkg[t] * 8) * 384 + tcol[t];
            #pragma unroll
            for (int j = 0; j < 8; ++j) rr[t][j] = wp[(size_t)j * 384];
        }
    };
    loadB(0);

    f32x4 acc[12];
    #pragma unroll
    for (int f = 0; f < 12; ++f) { acc[f][0]=0.f; acc[f][1]=0.f; acc[f][2]=0.f; acc[f][3]=0.f; }

    #pragma unroll 1
    for (int ck = 0; ck < 6; ++ck) {
        __syncthreads();
        #pragma unroll
        for (int t = 0; t < 6; ++t) {
            bf16x8 h, l; split8(rr[t], h, l);
            *(bf16x8*)((char*)bt_hi + swz(tcol[t], tkg[t])) = h;
            *(bf16x8*)((char*)bt_lo + swz(tcol[t], tkg[t])) = l;
        }
        __syncthreads();
        if (ck < 5) loadB(ck + 1);
        #pragma unroll
        for (int ks = 0; ks < 2; ++ks) {
            float av[8];
            const float* xp = xr + ck * 64 + ks * 32 + kq * 8;
            float4 a0 = *(const float4*)xp;
            float4 a1 = *(const float4*)(xp + 4);
            av[0]=a0.x; av[1]=a0.y; av[2]=a0.z; av[3]=a0.w;
            av[4]=a1.x; av[5]=a1.y; av[6]=a1.z; av[7]=a1.w;
            bf16x8 ah, al; split8(av, ah, al);
            #pragma unroll
            for (int f = 0; f < 12; ++f) {
                int n = wn * 192 + f * 16 + ln;
                int off = swz(n, ks * 4 + kq);
                bf16x8 bh = *(const bf16x8*)((char*)bt_hi + off);
                bf16x8 bl = *(const bf16x8*)((char*)bt_lo + off);
                acc[f] = __builtin_amdgcn_mfma_f32_16x16x32_bf16(ah, bh, acc[f], 0, 0, 0);
                acc[f] = __builtin_amdgcn_mfma_f32_16x16x32_bf16(ah, bl, acc[f], 0, 0, 0);
                acc[f] = __builtin_amdgcn_mfma_f32_16x16x32_bf16(al, bh, acc[f], 0, 0, 0);
            }
        }
    }
    __syncthreads();

    #pragma unroll
    for (int f = 0; f < 12; ++f) {
        int n = wn * 192 + f * 16 + ln;
        float pb = proj_b[n];
        #pragma unroll
        for (int r = 0; r < 4; ++r)
            out[(tok0 + wm * 16 + kq * 4 + r) * 384 + n] = acc[f][r] + pb;
    }
}

extern "C" void kernel_launch(void* const* d_in, const int* in_sizes, int n_in,
                              void* d_out, int out_size, void* d_ws, size_t ws_size,
                              hipStream_t stream) {
    const float* x         = (const float*)d_in[0];
    const float* qkv_w     = (const float*)d_in[1];
    const float* qkv_b     = (const float*)d_in[2];
    const float* proj_w    = (const float*)d_in[3];
    const float* proj_b    = (const float*)d_in[4];
    const float* rel_table = (const float*)d_in[5];
    float* out = (float*)d_out;
    char* wsc = (char*)d_ws;

    if (ws_size >= WS_NEED) {
        hipLaunchKernelGGL(prep_kernel, dim3(1536), dim3(384), 0, stream,
                           qkv_w, proj_w, wsc);
        hipLaunchKernelGGL(qkv_gemm_kernel, dim3(3072), dim3(512), 0, stream,
                           x, wsc, qkv_b, wsc);
        hipLaunchKernelGGL(attn_core_kernel, dim3(1024), dim3(256), 0, stream,
                           wsc, rel_table, out);
        hipLaunchKernelGGL(proj_kernel, dim3(784), dim3(512), 0, stream,
                           wsc, proj_b, out);
    } else {
        hipLaunchKernelGGL(wmsa_attn_kernel, dim3(1024), dim3(512), 0, stream,
                           x, qkv_w, qkv_b, rel_table, out);
        hipLaunchKernelGGL(wmsa_proj_kernel, dim3(784), dim3(512), 0, stream,
                           proj_w, proj_b, out);
    }
}

// Round 20
// 420.577 us; speedup vs baseline: 1.1773x; 1.0210x over previous
//
#include <hip/hip_runtime.h>
#include <hip/hip_bf16.h>

typedef unsigned short u16;
typedef __attribute__((ext_vector_type(8))) short bf16x8;
typedef __attribute__((ext_vector_type(4))) float f32x4;

#define NH 12
#define SCALE 0.1767766952966369f

// ---- ws layout (bytes) ----
#define UNIT 20992
#define WS_R0    ((size_t)0)
#define WS_QKVB  ((size_t)12288 * UNIT)                 // 257,949,696
#define WS_PROJB (WS_QKVB + (size_t)3 * 12 * 49152)     // +1,769,472
#define WS_NEED  (WS_PROJB + (size_t)12 * 49152)        // = 260,308,992

// split fp32 -> bf16 hi/lo via native RNE casts
__device__ __forceinline__ void split2(float x, u16& h, u16& l) {
    __hip_bfloat16 hb = __float2bfloat16(x);
    float hf = __bfloat162float(hb);
    __hip_bfloat16 lb = __float2bfloat16(x - hf);
    h = __bfloat16_as_ushort(hb);
    l = __bfloat16_as_ushort(lb);
}
__device__ __forceinline__ void split8(const float* v, bf16x8& hi, bf16x8& lo) {
    #pragma unroll
    for (int j = 0; j < 8; ++j) {
        u16 h, l; split2(v[j], h, l);
        hi[j] = (short)h; lo[j] = (short)l;
    }
}

// async global->LDS, 16B per lane
__device__ __forceinline__ void gload16(const char* g, char* l) {
    __builtin_amdgcn_global_load_lds(
        (const __attribute__((address_space(1))) unsigned*)g,
        (__attribute__((address_space(3))) unsigned*)l, 16, 0, 0);
}

// fallback-path swizzle
__device__ __forceinline__ int swz(int row, int g) {
    return row * 128 + (((g ^ (row & 7)) & 7) << 4);
}

// ===========================================================================
// prep: pre-split weights into FRAGMENT-MAJOR image chunks in ws (unchanged).
// ===========================================================================
__global__ __launch_bounds__(384) void prep_kernel(
    const float* __restrict__ qkv_w, const float* __restrict__ proj_w,
    char* __restrict__ ws)
{
    const int b = blockIdx.x, row = threadIdx.x;
    float w; size_t base;
    int kl;
    if (b < 1152) {
        int s = b / 384, r = b % 384, ck = r / 32; kl = r % 32;
        w = qkv_w[(size_t)(ck * 32 + kl) * 1152 + s * 384 + row];
        base = WS_QKVB + (size_t)(s * 12 + ck) * 49152;
    } else {
        int b1 = b - 1152, ck = b1 / 32; kl = b1 % 32;
        w = proj_w[(size_t)(ck * 32 + kl) * 384 + row];
        base = WS_PROJB + (size_t)ck * 49152;
    }
    u16 h, l; split2(w, h, l);
    int o = ((row >> 4) * 4 + (kl >> 3)) * 256 + (row & 15) * 16 + (kl & 7) * 2;
    *(u16*)(ws + base + o)         = h;
    *(u16*)(ws + base + 24576 + o) = l;
}

// ===========================================================================
// QKV GEMM: R16 tile (TWO windows M=128 x N=192, BK=32) + T4 counted-vmcnt
// + T1 bijective XCD swizzle (3072 = 8 x 384): all 6 N-tiles of a window
// pair land on ONE XCD so the pair's x rows are fetched once per L2.
// block=512 (4M x 2N waves, 2 blocks/CU).
// ===========================================================================
__global__ __launch_bounds__(512, 4) void qkv_gemm_kernel(
    const float* __restrict__ x, const char* __restrict__ wsB,
    const float* __restrict__ qkv_b, char* __restrict__ ws)
{
    __shared__ __align__(16) char bt[49152];   // 2 buffers x 24576

    const int bid0 = blockIdx.x;
    const int bid = (bid0 & 7) * 384 + (bid0 >> 3);   // bijective XCD chunking
    const int nt = bid % 6, s = nt >> 1, lt = nt & 1;
    const int pair = bid / 6;
    const int tid = threadIdx.x, lane = tid & 63;
    const int wv = tid >> 6;
    const int wm = wv >> 1, wn = wv & 1;
    const int ln = lane & 15, kq = lane >> 4;

    const float* xr[2];
    #pragma unroll
    for (int am = 0; am < 2; ++am) {
        int wwin = pair * 2 + am;
        int bi = wwin >> 6, win = wwin & 63;
        int wy = win >> 3, wx = win & 7;
        int arow = wm * 16 + ln;
        int ar = (arow < 49) ? arow : 0;
        int Y = wy * 7 + ar / 7, X = wx * 7 + ar % 7;
        xr[am] = x + (size_t)((bi * 56 + Y) * 56 + X) * 384 + kq * 8;
    }
    const char* wB = wsB + WS_QKVB + (size_t)s * 12 * 49152;

    // 24 segs x 1024 B per chunk; each wave issues 3 gload16
    auto stage = [&](int ck, int buf) {
        const char* cb = wB + (size_t)ck * 49152 + (size_t)lt * 12288;
        #pragma unroll
        for (int i = 0; i < 3; ++i) {
            int seg = wv + i * 8;
            const char* src = (seg < 12) ? (cb + seg * 1024)
                                         : (cb + 24576 + (seg - 12) * 1024);
            gload16(src + lane * 16, bt + buf * 24576 + seg * 1024);
        }
    };

    // prologue: stage chunk0 (3 loads) + A chunk0 prefetch (4 loads)
    stage(0, 0);
    float4 a0A = *(const float4*)(xr[0]);
    float4 a1A = *(const float4*)(xr[0] + 4);
    float4 a0B = *(const float4*)(xr[1]);
    float4 a1B = *(const float4*)(xr[1] + 4);

    f32x4 acc[2][6];
    #pragma unroll
    for (int am = 0; am < 2; ++am)
        #pragma unroll
        for (int f = 0; f < 6; ++f) { acc[am][f][0]=0.f; acc[am][f][1]=0.f; acc[am][f][2]=0.f; acc[am][f][3]=0.f; }

    #pragma unroll 1
    for (int ck = 0; ck < 12; ++ck) {
        const int cur = (ck & 1) * 24576;
        float4 n0A, n1A, n0B, n1B;
        if (ck < 11) {
            stage(ck + 1, (ck & 1) ^ 1);               // 3 loads, other buf
            n0A = *(const float4*)(xr[0] + (ck + 1) * 32);   // 4 loads
            n1A = *(const float4*)(xr[0] + (ck + 1) * 32 + 4);
            n0B = *(const float4*)(xr[1] + (ck + 1) * 32);
            n1B = *(const float4*)(xr[1] + (ck + 1) * 32 + 4);
            asm volatile("s_waitcnt vmcnt(7)" ::: "memory");
        } else {
            asm volatile("s_waitcnt vmcnt(0)" ::: "memory");
        }
        __builtin_amdgcn_s_barrier();
        __builtin_amdgcn_sched_barrier(0);

        bf16x8 ah0, al0, ah1, al1;
        {
            float av[8];
            av[0]=a0A.x; av[1]=a0A.y; av[2]=a0A.z; av[3]=a0A.w;
            av[4]=a1A.x; av[5]=a1A.y; av[6]=a1A.z; av[7]=a1A.w;
            split8(av, ah0, al0);
            av[0]=a0B.x; av[1]=a0B.y; av[2]=a0B.z; av[3]=a0B.w;
            av[4]=a1B.x; av[5]=a1B.y; av[6]=a1B.z; av[7]=a1B.w;
            split8(av, ah1, al1);
        }
        #pragma unroll
        for (int f = 0; f < 6; ++f) {
            int off = cur + ((wn * 6 + f) * 4 + kq) * 256 + ln * 16;
            bf16x8 bh = *(const bf16x8*)(bt + off);
            bf16x8 bl = *(const bf16x8*)(bt + off + 12288);
            acc[0][f] = __builtin_amdgcn_mfma_f32_16x16x32_bf16(ah0, bh, acc[0][f], 0, 0, 0);
            acc[0][f] = __builtin_amdgcn_mfma_f32_16x16x32_bf16(ah0, bl, acc[0][f], 0, 0, 0);
            acc[0][f] = __builtin_amdgcn_mfma_f32_16x16x32_bf16(al0, bh, acc[0][f], 0, 0, 0);
            acc[1][f] = __builtin_amdgcn_mfma_f32_16x16x32_bf16(ah1, bh, acc[1][f], 0, 0, 0);
            acc[1][f] = __builtin_amdgcn_mfma_f32_16x16x32_bf16(ah1, bl, acc[1][f], 0, 0, 0);
            acc[1][f] = __builtin_amdgcn_mfma_f32_16x16x32_bf16(al1, bh, acc[1][f], 0, 0, 0);
        }
        __builtin_amdgcn_sched_barrier(0);
        __builtin_amdgcn_s_barrier();
        if (ck < 11) { a0A = n0A; a1A = n1A; a0B = n0B; a1B = n1B; }
    }

    // ---- epilogue: streaming writes into both windows' units ----
    #pragma unroll
    for (int am = 0; am < 2; ++am) {
        int wwin = pair * 2 + am;
        u16* ub = (u16*)(ws + WS_R0 + (size_t)(wwin * 12) * UNIT);
        #pragma unroll
        for (int f = 0; f < 6; ++f) {
            int n_local = lt * 192 + wn * 96 + f * 16 + ln;
            int hh = n_local >> 5, dd = n_local & 31;
            float bias = qkv_b[s * 384 + n_local];
            u16* u = ub + (size_t)hh * (UNIT / 2);
            #pragma unroll
            for (int r = 0; r < 4; ++r) {
                int wrow = wm * 16 + kq * 4 + r;
                if (wrow < 49) {
                    float val = acc[am][f][r] + bias;
                    if (s == 0) val *= SCALE;
                    u16 h, l; split2(val, h, l);
                    if (s == 0)      { u[wrow * 32 + dd] = h;        u[1568 + wrow * 32 + dd] = l; }
                    else if (s == 1) { u[3136 + wrow * 32 + dd] = h; u[4704 + wrow * 32 + dd] = l; }
                    else             { u[6272 + wrow * 32 + dd] = h; u[8320 + wrow * 32 + dd] = l; }
                }
            }
        }
    }
}

// ===========================================================================
// attention core: one block per GLOBAL window (256 thr = 4 waves). Unchanged.
// ===========================================================================
__global__ __launch_bounds__(256) void attn_core_kernel(
    const char* __restrict__ ws, const float* __restrict__ rel_table,
    float* __restrict__ out)
{
    __shared__ __align__(16) float pt[64][68];
    __shared__ __align__(16) float rel_all[2048];
    __shared__ float pmax[4][64];
    __shared__ float psum[4][64];
    __shared__ __align__(16) u16 vth[32][72];
    __shared__ __align__(16) u16 vtl[32][72];

    const int wi = blockIdx.x, bi = wi >> 6, win = wi & 63;
    const int wy = win >> 3, wx = win & 7;
    const int tid = threadIdx.x, lane = tid & 63, wv = tid >> 6;
    const int ln = lane & 15, kq = lane >> 4;

    for (int i = tid; i < 2028; i += 256) rel_all[i] = rel_table[i];
    for (int i = tid; i < 32 * 72; i += 256) { ((u16*)vth)[i] = 0; ((u16*)vtl)[i] = 0; }

    int m7[4], mr[4], outY[4], outX[4];
    bool mok[4];
    #pragma unroll
    for (int r = 0; r < 4; ++r) {
        int m = wv * 16 + kq * 4 + r;
        mok[r] = (m < 49);
        int a = mok[r] ? m : 0;
        m7[r] = a / 7; mr[r] = a % 7;
        outY[r] = wy * 7 + m7[r]; outX[r] = wx * 7 + mr[r];
    }
    int n7[4], nr[4];
    #pragma unroll
    for (int nt = 0; nt < 4; ++nt) {
        int n = nt * 16 + ln, a = (n < 49) ? n : 0;
        n7[nt] = a / 7; nr[nt] = a % 7;
    }
    const int mK = wv * 16 + ln;
    bf16x8 zz;
    #pragma unroll
    for (int j = 0; j < 8; ++j) zz[j] = 0;

    __syncthreads();

    for (int h = 0; h < NH; ++h) {
        const u16* u = (const u16*)(ws + WS_R0 + (size_t)(wi * 12 + h) * UNIT);
        const u16* qhi = u,        * qlo = u + 1568;
        const u16* khi = u + 3136, * klo = u + 4704;
        const u16* vhi = u + 6272, * vlo = u + 8320;

        if (tid < 196) {
            int row = tid >> 2, d0 = (tid & 3) * 8;
            bf16x8 v8h = *(const bf16x8*)(vhi + row * 32 + d0);
            bf16x8 v8l = *(const bf16x8*)(vlo + row * 32 + d0);
            #pragma unroll
            for (int j = 0; j < 8; ++j) {
                vth[d0 + j][row] = (u16)v8h[j];
                vtl[d0 + j][row] = (u16)v8l[j];
            }
        }

        bf16x8 kh = zz, kl = zz;
        if (mK < 49) {
            kh = *(const bf16x8*)(khi + mK * 32 + kq * 8);
            kl = *(const bf16x8*)(klo + mK * 32 + kq * 8);
        }
        f32x4 accs[4];
        #pragma unroll
        for (int nt = 0; nt < 4; ++nt) {
            int n = nt * 16 + ln;
            bf16x8 qh = zz, ql = zz;
            if (n < 49) {
                qh = *(const bf16x8*)(qhi + n * 32 + kq * 8);
                ql = *(const bf16x8*)(qlo + n * 32 + kq * 8);
            }
            f32x4 z; z[0]=0.f; z[1]=0.f; z[2]=0.f; z[3]=0.f;
            z = __builtin_amdgcn_mfma_f32_16x16x32_bf16(kh, qh, z, 0, 0, 0);
            z = __builtin_amdgcn_mfma_f32_16x16x32_bf16(kh, ql, z, 0, 0, 0);
            z = __builtin_amdgcn_mfma_f32_16x16x32_bf16(kl, qh, z, 0, 0, 0);
            accs[nt] = z;
        }

        float e[4][4], gmax[4], ginv[4];
        #pragma unroll
        for (int nt = 0; nt < 4; ++nt) {
            float lm = -3.4e38f;
            #pragma unroll
            for (int r = 0; r < 4; ++r) if (mok[r]) lm = fmaxf(lm, accs[nt][r]);
            lm = fmaxf(lm, __shfl_xor(lm, 16));
            lm = fmaxf(lm, __shfl_xor(lm, 32));
            if (kq == 0) pmax[wv][nt * 16 + ln] = lm;
        }
        __syncthreads();
        #pragma unroll
        for (int nt = 0; nt < 4; ++nt) {
            int n = nt * 16 + ln;
            gmax[nt] = fmaxf(fmaxf(pmax[0][n], pmax[1][n]), fmaxf(pmax[2][n], pmax[3][n]));
            float ls = 0.f;
            #pragma unroll
            for (int r = 0; r < 4; ++r) {
                e[nt][r] = mok[r] ? __expf(accs[nt][r] - gmax[nt]) : 0.f;
                ls += e[nt][r];
            }
            ls += __shfl_xor(ls, 16);
            ls += __shfl_xor(ls, 32);
            if (kq == 0) psum[wv][nt * 16 + ln] = ls;
        }
        __syncthreads();
        #pragma unroll
        for (int nt = 0; nt < 4; ++nt) {
            int n = nt * 16 + ln;
            ginv[nt] = 1.f / (psum[0][n] + psum[1][n] + psum[2][n] + psum[3][n]);
            #pragma unroll
            for (int r = 0; r < 4; ++r) {
                float val = 0.f;
                if (mok[r]) {
                    int bidx = (n7[nt] - m7[r] + 6) * 13 + (nr[nt] - mr[r] + 6);
                    val = e[nt][r] * ginv[nt] + rel_all[bidx * NH + h];
                }
                pt[n][wv * 16 + kq * 4 + r] = val;
            }
        }
        __syncthreads();

        bf16x8 pah[2], pal[2];
        #pragma unroll
        for (int mc = 0; mc < 2; ++mc) {
            const float* pp = &pt[wv * 16 + ln][mc * 32 + kq * 8];
            float v[8];
            float4 a0 = *(const float4*)pp;
            float4 a1 = *(const float4*)(pp + 4);
            v[0]=a0.x; v[1]=a0.y; v[2]=a0.z; v[3]=a0.w;
            v[4]=a1.x; v[5]=a1.y; v[6]=a1.z; v[7]=a1.w;
            split8(v, pah[mc], pal[mc]);
        }
        f32x4 acco[2];
        #pragma unroll
        for (int dt = 0; dt < 2; ++dt) { acco[dt][0]=0.f; acco[dt][1]=0.f; acco[dt][2]=0.f; acco[dt][3]=0.f; }
        #pragma unroll
        for (int dt = 0; dt < 2; ++dt) {
            int d = dt * 16 + ln;
            #pragma unroll
            for (int mc = 0; mc < 2; ++mc) {
                bf16x8 vh = *(const bf16x8*)(&vth[d][mc * 32 + kq * 8]);
                bf16x8 vl = *(const bf16x8*)(&vtl[d][mc * 32 + kq * 8]);
                acco[dt] = __builtin_amdgcn_mfma_f32_16x16x32_bf16(pah[mc], vh, acco[dt], 0, 0, 0);
                acco[dt] = __builtin_amdgcn_mfma_f32_16x16x32_bf16(pah[mc], vl, acco[dt], 0, 0, 0);
                acco[dt] = __builtin_amdgcn_mfma_f32_16x16x32_bf16(pal[mc], vh, acco[dt], 0, 0, 0);
            }
        }
        #pragma unroll
        for (int r = 0; r < 4; ++r) {
            if (mok[r]) {
                size_t base = (size_t)((bi * 56 + outY[r]) * 56 + outX[r]) * 384 + h * 32;
                out[base + ln]      = acco[0][r];
                out[base + 16 + ln] = acco[1][r];
            }
        }
        __syncthreads();
    }
}

// ===========================================================================
// proj: BK=32, reg-staged frag-major image, IN PLACE (R10-proven).
// ===========================================================================
__global__ __launch_bounds__(512) void proj_kernel(
    const char* __restrict__ wsB, const float* __restrict__ proj_b,
    float* __restrict__ out)
{
    __shared__ __align__(16) char bt[49152];

    const int tid = threadIdx.x, lane = tid & 63;
    const int wv = tid >> 6, wm = wv >> 1, wn = wv & 1;
    const int ln = lane & 15, kq = lane >> 4;
    const size_t tok0 = (size_t)blockIdx.x * 64;
    const float* xr = out + (tok0 + wm * 16 + ln) * 384 + kq * 8;
    const char* wB = wsB + WS_PROJB;

    bf16x8 st[6];
    #pragma unroll
    for (int i = 0; i < 6; ++i)
        st[i] = *(const bf16x8*)(wB + (size_t)tid * 16 + i * 8192);

    float4 a0 = *(const float4*)(xr);
    float4 a1 = *(const float4*)(xr + 4);

    f32x4 acc[12];
    #pragma unroll
    for (int f = 0; f < 12; ++f) { acc[f][0]=0.f; acc[f][1]=0.f; acc[f][2]=0.f; acc[f][3]=0.f; }

    #pragma unroll 1
    for (int ck = 0; ck < 12; ++ck) {
        __syncthreads();
        #pragma unroll
        for (int i = 0; i < 6; ++i)
            *(bf16x8*)(bt + tid * 16 + i * 8192) = st[i];
        __syncthreads();
        float4 na0, na1;
        if (ck < 11) {
            const char* nb = wB + (size_t)(ck + 1) * 49152;
            #pragma unroll
            for (int i = 0; i < 6; ++i)
                st[i] = *(const bf16x8*)(nb + (size_t)tid * 16 + i * 8192);
            na0 = *(const float4*)(xr + (ck + 1) * 32);
            na1 = *(const float4*)(xr + (ck + 1) * 32 + 4);
        }
        float av[8];
        av[0]=a0.x; av[1]=a0.y; av[2]=a0.z; av[3]=a0.w;
        av[4]=a1.x; av[5]=a1.y; av[6]=a1.z; av[7]=a1.w;
        bf16x8 ah, al; split8(av, ah, al);
        #pragma unroll
        for (int f = 0; f < 12; ++f) {
            int off = (wn * 12 + f) * 1024 + kq * 256 + ln * 16;
            bf16x8 bh = *(const bf16x8*)(bt + off);
            bf16x8 bl = *(const bf16x8*)(bt + 24576 + off);
            acc[f] = __builtin_amdgcn_mfma_f32_16x16x32_bf16(ah, bh, acc[f], 0, 0, 0);
            acc[f] = __builtin_amdgcn_mfma_f32_16x16x32_bf16(ah, bl, acc[f], 0, 0, 0);
            acc[f] = __builtin_amdgcn_mfma_f32_16x16x32_bf16(al, bh, acc[f], 0, 0, 0);
        }
        if (ck < 11) { a0 = na0; a1 = na1; }
    }
    __syncthreads();

    #pragma unroll
    for (int f = 0; f < 12; ++f) {
        int n = wn * 192 + f * 16 + ln;
        float pb = proj_b[n];
        #pragma unroll
        for (int r = 0; r < 4; ++r)
            out[(tok0 + wm * 16 + kq * 4 + r) * 384 + n] = acc[f][r] + pb;
    }
}

// ===========================================================================
// PATH B fallback (small ws): R4 fused per-window kernel + runtime-split proj.
// ===========================================================================
__global__ __launch_bounds__(512) void wmsa_attn_kernel(
    const float* __restrict__ x, const float* __restrict__ qkv_w,
    const float* __restrict__ qkv_b, const float* __restrict__ rel_table,
    float* __restrict__ out)
{
    __shared__ __align__(16) char smem[55936];
    u16* bt_hi = (u16*)smem;
    u16* bt_lo = (u16*)(smem + 24576);
    float* qs  = (float*)smem;
    float* kss = (float*)(smem + 14976);
    float* vst = (float*)(smem + 29952);
    float* at  = (float*)(smem + 44288);

    const int wi = blockIdx.x, bi = wi >> 6, win = wi & 63;
    const int wy = win >> 3, wx = win & 7;
    const int tid = threadIdx.x, lane = tid & 63;
    const int wv = tid >> 6, wm = wv >> 1, wn = wv & 1;
    const int ln = lane & 15, kq = lane >> 4;
    const int arow = wm * 16 + ln;

    int Y = wy * 7, X = wx * 7;
    if (arow < 49) { Y += arow / 7; X += arow % 7; }
    const float* xr = x + (size_t)((bi * 56 + Y) * 56 + X) * 384;

    int tcol[3], tkg[3];
    #pragma unroll
    for (int t = 0; t < 3; ++t) { int idx = tid + t * 512; tcol[t] = idx % 192; tkg[t] = idx / 192; }
    float rr[3][8];
    auto loadB = [&](int p, int ck) {
        #pragma unroll
        for (int t = 0; t < 3; ++t) {
            int c = tcol[t];
            int n = (c >> 6) * 384 + p * 64 + (c & 63);
            const float* wp = qkv_w + (size_t)(ck * 64 + tkg[t] * 8) * 1152 + n;
            #pragma unroll
            for (int j = 0; j < 8; ++j) rr[t][j] = wp[(size_t)j * 1152];
        }
    };
    loadB(0, 0);

    #pragma unroll 1
    for (int p = 0; p < 6; ++p) {
        f32x4 acc[6];
        #pragma unroll
        for (int f = 0; f < 6; ++f) { acc[f][0]=0.f; acc[f][1]=0.f; acc[f][2]=0.f; acc[f][3]=0.f; }
        #pragma unroll 1
        for (int ck = 0; ck < 6; ++ck) {
            __syncthreads();
            #pragma unroll
            for (int t = 0; t < 3; ++t) {
                bf16x8 h, l;
                split8(rr[t], h, l);
                *(bf16x8*)((char*)bt_hi + swz(tcol[t], tkg[t])) = h;
                *(bf16x8*)((char*)bt_lo + swz(tcol[t], tkg[t])) = l;
            }
            __syncthreads();
            if (ck < 5) loadB(p, ck + 1);
            else if (p < 5) loadB(p + 1, 0);
            #pragma unroll
            for (int ks = 0; ks < 2; ++ks) {
                float av[8];
                const float* xp = xr + ck * 64 + ks * 32 + kq * 8;
                float4 a0 = *(const float4*)xp;
                float4 a1 = *(const float4*)(xp + 4);
                av[0]=a0.x; av[1]=a0.y; av[2]=a0.z; av[3]=a0.w;
                av[4]=a1.x; av[5]=a1.y; av[6]=a1.z; av[7]=a1.w;
                bf16x8 ah, al; split8(av, ah, al);
                #pragma unroll
                for (int f = 0; f < 6; ++f) {
                    int n = wn * 96 + f * 16 + ln;
                    int off = swz(n, ks * 4 + kq);
                    bf16x8 bh = *(const bf16x8*)((char*)bt_hi + off);
                    bf16x8 bl = *(const bf16x8*)((char*)bt_lo + off);
                    acc[f] = __builtin_amdgcn_mfma_f32_16x16x32_bf16(ah, bh, acc[f], 0, 0, 0);
                    acc[f] = __builtin_amdgcn_mfma_f32_16x16x32_bf16(ah, bl, acc[f], 0, 0, 0);
                    acc[f] = __builtin_amdgcn_mfma_f32_16x16x32_bf16(al, bh, acc[f], 0, 0, 0);
                }
            }
        }
        __syncthreads();
        #pragma unroll
        for (int f = 0; f < 6; ++f) {
            int c = wn * 96 + f * 16 + ln;
            int m = c >> 6, d = c & 63, hh = d >> 5, dd = d & 31;
            float bias = qkv_b[m * 384 + p * 64 + d];
            #pragma unroll
            for (int r = 0; r < 4; ++r) {
                int row = wm * 16 + kq * 4 + r;
                if (row < 52) {
                    float val = acc[f][r] + bias;
                    if (m == 0)      qs [(hh * 52 + row) * 36 + dd] = val * SCALE;
                    else if (m == 1) kss[(hh * 52 + row) * 36 + dd] = val;
                    else             vst[(hh * 32 + dd) * 56 + row] = val;
                }
            }
        }
        __syncthreads();
        for (int hh = 0; hh < 2; ++hh) {
            const int h = p * 2 + hh;
            const float* qsh = qs  + hh * 52 * 36;
            const float* ksh = kss + hh * 52 * 36;
            const float* vsh = vst + hh * 32 * 56;
            if (tid < 169) {
                const int n0 = (tid / 13) * 4, m0 = (tid % 13) * 4;
                float s[4][4] = {};
                #pragma unroll
                for (int k = 0; k < 32; k += 4) {
                    float4 qa[4], kb[4];
                    #pragma unroll
                    for (int i = 0; i < 4; ++i) qa[i] = *(const float4*)&qsh[(n0 + i) * 36 + k];
                    #pragma unroll
                    for (int j = 0; j < 4; ++j) kb[j] = *(const float4*)&ksh[(m0 + j) * 36 + k];
                    #pragma unroll
                    for (int i = 0; i < 4; ++i)
                        #pragma unroll
                        for (int j = 0; j < 4; ++j)
                            s[i][j] += qa[i].x * kb[j].x + qa[i].y * kb[j].y +
                                       qa[i].z * kb[j].z + qa[i].w * kb[j].w;
                }
                #pragma unroll
                for (int i = 0; i < 4; ++i)
                    #pragma unroll
                    for (int j = 0; j < 4; ++j)
                        at[(n0 + i) * 56 + m0 + j] = s[i][j];
            }
            __syncthreads();
            for (int r = wv; r < 49; r += 8) {
                float v = (lane < 49) ? at[r * 56 + lane] : -3.4e38f;
                float mx = v;
                #pragma unroll
                for (int off = 32; off; off >>= 1) mx = fmaxf(mx, __shfl_xor(mx, off));
                float ex = (lane < 49) ? __expf(v - mx) : 0.f;
                float ssum = ex;
                #pragma unroll
                for (int off = 32; off; off >>= 1) ssum += __shfl_xor(ssum, off);
                if (lane < 52) {
                    float res = 0.f;
                    if (lane < 49) {
                        int py = r / 7, px = r % 7, qy = lane / 7, qx = lane % 7;
                        int bidx = (py - qy + 6) * 13 + (px - qx + 6);
                        res = ex / ssum + rel_table[bidx * NH + h];
                    }
                    at[r * 56 + lane] = res;
                }
            }
            __syncthreads();
            if (tid < 208) {
                const int n0 = (tid / 16) * 4, d0 = (tid % 16) * 2;
                float o[4][2] = {};
                #pragma unroll
                for (int m2 = 0; m2 < 52; m2 += 4) {
                    float4 pa[4], vb2[2];
                    #pragma unroll
                    for (int i = 0; i < 4; ++i) pa[i] = *(const float4*)&at[(n0 + i) * 56 + m2];
                    #pragma unroll
                    for (int j = 0; j < 2; ++j) vb2[j] = *(const float4*)&vsh[(d0 + j) * 56 + m2];
                    #pragma unroll
                    for (int i = 0; i < 4; ++i)
                        #pragma unroll
                        for (int j = 0; j < 2; ++j)
                            o[i][j] += pa[i].x * vb2[j].x + pa[i].y * vb2[j].y +
                                       pa[i].z * vb2[j].z + pa[i].w * vb2[j].w;
                }
                #pragma unroll
                for (int i = 0; i < 4; ++i) {
                    int n = n0 + i;
                    if (n < 49) {
                        int Yo = wy * 7 + n / 7, Xo = wx * 7 + n % 7;
                        size_t base = (size_t)((bi * 56 + Yo) * 56 + Xo) * 384 + h * 32 + d0;
                        *(float2*)(out + base) = make_float2(o[i][0], o[i][1]);
                    }
                }
            }
            __syncthreads();
        }
    }
}

__global__ __launch_bounds__(512) void wmsa_proj_kernel(
    const float* __restrict__ proj_w, const float* __restrict__ proj_b,
    float* __restrict__ out)
{
    __shared__ __align__(16) char smem[98304];
    u16* bt_hi = (u16*)smem;
    u16* bt_lo = (u16*)(smem + 49152);

    const int tid = threadIdx.x, lane = tid & 63;
    const int wv = tid >> 6, wm = wv >> 1, wn = wv & 1;
    const int ln = lane & 15, kq = lane >> 4;
    const size_t tok0 = (size_t)blockIdx.x * 64;
    const float* xr = out + (tok0 + wm * 16 + ln) * 384;

    int tcol[6], tkg[6];
    #pragma unroll
    for (int t = 0; t < 6; ++t) { int idx = tid + t * 512; tcol[t] = idx % 384; tkg[t] = idx / 384; }
    float rr[6][8];
    auto loadB = [&](int ck) {
        #pragma unroll
        for (int t = 0; t < 6; ++t) {
            const float* wp = proj_w + (size_t)(ck * 64 + tkg[t] * 8) * 384 + tcol[t];
            #pragma unroll
            for (int j = 0; j < 8; ++j) rr[t][j] = wp[(size_t)j * 384];
        }
    };
    loadB(0);

    f32x4 acc[12];
    #pragma unroll
    for (int f = 0; f < 12; ++f) { acc[f][0]=0.f; acc[f][1]=0.f; acc[f][2]=0.f; acc[f][3]=0.f; }

    #pragma unroll 1
    for (int ck = 0; ck < 6; ++ck) {
        __syncthreads();
        #pragma unroll
        for (int t = 0; t < 6; ++t) {
            bf16x8 h, l; split8(rr[t], h, l);
            *(bf16x8*)((char*)bt_hi + swz(tcol[t], tkg[t])) = h;
            *(bf16x8*)((char*)bt_lo + swz(tcol[t], tkg[t])) = l;
        }
        __syncthreads();
        if (ck < 5) loadB(ck + 1);
        #pragma unroll
        for (int ks = 0; ks < 2; ++ks) {
            float av[8];
            const float* xp = xr + ck * 64 + ks * 32 + kq * 8;
            float4 a0 = *(const float4*)xp;
            float4 a1 = *(const float4*)(xp + 4);
            av[0]=a0.x; av[1]=a0.y; av[2]=a0.z; av[3]=a0.w;
            av[4]=a1.x; av[5]=a1.y; av[6]=a1.z; av[7]=a1.w;
            bf16x8 ah, al; split8(av, ah, al);
            #pragma unroll
            for (int f = 0; f < 12; ++f) {
                int n = wn * 192 + f * 16 + ln;
                int off = swz(n, ks * 4 + kq);
                bf16x8 bh = *(const bf16x8*)((char*)bt_hi + off);
                bf16x8 bl = *(const bf16x8*)((char*)bt_lo + off);
                acc[f] = __builtin_amdgcn_mfma_f32_16x16x32_bf16(ah, bh, acc[f], 0, 0, 0);
                acc[f] = __builtin_amdgcn_mfma_f32_16x16x32_bf16(ah, bl, acc[f], 0, 0, 0);
                acc[f] = __builtin_amdgcn_mfma_f32_16x16x32_bf16(al, bh, acc[f], 0, 0, 0);
            }
        }
    }
    __syncthreads();

    #pragma unroll
    for (int f = 0; f < 12; ++f) {
        int n = wn * 192 + f * 16 + ln;
        float pb = proj_b[n];
        #pragma unroll
        for (int r = 0; r < 4; ++r)
            out[(tok0 + wm * 16 + kq * 4 + r) * 384 + n] = acc[f][r] + pb;
    }
}

extern "C" void kernel_launch(void* const* d_in, const int* in_sizes, int n_in,
                              void* d_out, int out_size, void* d_ws, size_t ws_size,
                              hipStream_t stream) {
    const float* x         = (const float*)d_in[0];
    const float* qkv_w     = (const float*)d_in[1];
    const float* qkv_b     = (const float*)d_in[2];
    const float* proj_w    = (const float*)d_in[3];
    const float* proj_b    = (const float*)d_in[4];
    const float* rel_table = (const float*)d_in[5];
    float* out = (float*)d_out;
    char* wsc = (char*)d_ws;

    if (ws_size >= WS_NEED) {
        hipLaunchKernelGGL(prep_kernel, dim3(1536), dim3(384), 0, stream,
                           qkv_w, proj_w, wsc);
        hipLaunchKernelGGL(qkv_gemm_kernel, dim3(3072), dim3(512), 0, stream,
                           x, wsc, qkv_b, wsc);
        hipLaunchKernelGGL(attn_core_kernel, dim3(1024), dim3(256), 0, stream,
                           wsc, rel_table, out);
        hipLaunchKernelGGL(proj_kernel, dim3(784), dim3(512), 0, stream,
                           wsc, proj_b, out);
    } else {
        hipLaunchKernelGGL(wmsa_attn_kernel, dim3(1024), dim3(512), 0, stream,
                           x, qkv_w, qkv_b, rel_table, out);
        hipLaunchKernelGGL(wmsa_proj_kernel, dim3(784), dim3(512), 0, stream,
                           proj_w, proj_b, out);
    }
}